// Round 1
// baseline (4835.438 us; speedup 1.0000x reference)
//
#include <hip/hip_runtime.h>
#include <math.h>

#define D_IN 128
#define HDIM 256

// ---------------------------------------------------------------------------
// zero a float buffer (grid-stride, float4)
// ---------------------------------------------------------------------------
__global__ __launch_bounds__(256) void zero_kernel(float4* __restrict__ p, int n4) {
    int i = blockIdx.x * 256 + threadIdx.x;
    int stride = gridDim.x * 256;
    for (; i < n4; i += stride) p[i] = make_float4(0.f, 0.f, 0.f, 0.f);
}

// ---------------------------------------------------------------------------
// edge scatter-add: agg[dst] += feat[src]   (one thread per (edge, 4 cols))
// LOGD4: log2(D/4)  (D=128 -> 5, D=256 -> 6)
// ---------------------------------------------------------------------------
template<int LOGD4>
__global__ __launch_bounds__(256) void scatter_add_kernel(
    const float* __restrict__ feat, const int* __restrict__ ei,
    float* __restrict__ agg, int E)
{
    const int D4 = 1 << LOGD4;
    const int D  = D4 * 4;
    int tid = blockIdx.x * 256 + threadIdx.x;
    int e = tid >> LOGD4;
    if (e >= E) return;
    int c = (tid & (D4 - 1)) << 2;
    int s = ei[e];
    int d = ei[E + e];
    const float4 v = *(const float4*)(feat + (long long)s * D + c);
    float* a = agg + (long long)d * D + c;
    atomicAdd(a + 0, v.x);
    atomicAdd(a + 1, v.y);
    atomicAdd(a + 2, v.z);
    atomicAdd(a + 3, v.w);
}

// ---------------------------------------------------------------------------
// OUT[r][c] = relu( (X[r]+ADD[r]) @ W + Bias )   X:[N][K]  W:[K][256]
// BM=64, BN=256 (full), BK=32. 256 threads: 64 col-groups x 4 row-groups,
// each thread owns 16 rows x 4 cols. LDS: A 8KB + W 32KB.
// ---------------------------------------------------------------------------
template<int K, bool HAS_ADD>
__global__ __launch_bounds__(256) void gemm_relu_kernel(
    const float* __restrict__ X, const float* __restrict__ ADD,
    const float* __restrict__ W, const float* __restrict__ Bias,
    float* __restrict__ OUT, int Nrows)
{
    __shared__ float As[64][32];
    __shared__ float Ws[32][256];
    const int t    = threadIdx.x;
    const int row0 = blockIdx.x * 64;
    const int tx   = t & 63;
    const int ty   = t >> 6;          // wave-uniform
    const int col0 = tx * 4;

    float acc[16][4];
#pragma unroll
    for (int i = 0; i < 16; ++i)
#pragma unroll
        for (int j = 0; j < 4; ++j) acc[i][j] = 0.f;

    for (int k0 = 0; k0 < K; k0 += 32) {
        // stage A tile (64x32): 512 float4, 2 per thread; fused z = X + ADD
#pragma unroll
        for (int i = 0; i < 2; ++i) {
            int idx = t + i * 256;
            int r = idx >> 3;
            int c = (idx & 7) << 2;
            int grow = row0 + r;
            float4 v = make_float4(0.f, 0.f, 0.f, 0.f);
            if (grow < Nrows) {
                v = *(const float4*)(X + (long long)grow * K + k0 + c);
                if (HAS_ADD) {
                    float4 u = *(const float4*)(ADD + (long long)grow * K + k0 + c);
                    v.x += u.x; v.y += u.y; v.z += u.z; v.w += u.w;
                }
            }
            *(float4*)&As[r][c] = v;
        }
        // stage W tile (32x256): 2048 float4, 8 per thread
#pragma unroll
        for (int i = 0; i < 8; ++i) {
            int idx = t + i * 256;
            int kk = idx >> 6;
            int c = (idx & 63) << 2;
            *(float4*)&Ws[kk][c] = *(const float4*)(W + (long long)(k0 + kk) * HDIM + c);
        }
        __syncthreads();

#pragma unroll
        for (int kk4 = 0; kk4 < 8; ++kk4) {
            float4 w0 = *(const float4*)&Ws[kk4 * 4 + 0][col0];
            float4 w1 = *(const float4*)&Ws[kk4 * 4 + 1][col0];
            float4 w2 = *(const float4*)&Ws[kk4 * 4 + 2][col0];
            float4 w3 = *(const float4*)&Ws[kk4 * 4 + 3][col0];
#pragma unroll
            for (int i = 0; i < 16; ++i) {
                float4 a = *(const float4*)&As[ty * 16 + i][kk4 * 4];  // wave-uniform: broadcast
                acc[i][0] += a.x * w0.x + a.y * w1.x + a.z * w2.x + a.w * w3.x;
                acc[i][1] += a.x * w0.y + a.y * w1.y + a.z * w2.y + a.w * w3.y;
                acc[i][2] += a.x * w0.z + a.y * w1.z + a.z * w2.z + a.w * w3.z;
                acc[i][3] += a.x * w0.w + a.y * w1.w + a.z * w2.w + a.w * w3.w;
            }
        }
        __syncthreads();
    }

    float4 b4 = *(const float4*)(Bias + col0);
#pragma unroll
    for (int i = 0; i < 16; ++i) {
        int grow = row0 + ty * 16 + i;
        if (grow < Nrows) {
            float4 o;
            o.x = fmaxf(acc[i][0] + b4.x, 0.f);
            o.y = fmaxf(acc[i][1] + b4.y, 0.f);
            o.z = fmaxf(acc[i][2] + b4.z, 0.f);
            o.w = fmaxf(acc[i][3] + b4.w, 0.f);
            *(float4*)(OUT + (long long)grow * HDIM + col0) = o;
        }
    }
}

// ---------------------------------------------------------------------------
// one block (256 thr) per graph: mean/max pool over [lo,hi) then 2-layer MLP
// ---------------------------------------------------------------------------
__global__ __launch_bounds__(256) void pool_mlp_kernel(
    const float* __restrict__ h2, const int* __restrict__ batch,
    const float* __restrict__ Wf1, const float* __restrict__ bf1,
    const float* __restrict__ Wf2, const float* __restrict__ bf2,
    float* __restrict__ out, int N)
{
    const int g = blockIdx.x;
    const int t = threadIdx.x;

    __shared__ int s_bounds[2];
    if (t < 2) {  // lower_bound(batch, g) and lower_bound(batch, g+1)
        int target = g + t;
        int lo = 0, hi = N;
        while (lo < hi) {
            int mid = (lo + hi) >> 1;
            if (batch[mid] < target) lo = mid + 1; else hi = mid;
        }
        s_bounds[t] = lo;
    }
    __syncthreads();
    const int lo = s_bounds[0], hi = s_bounds[1];
    const int cnt = hi - lo;

    float sum = 0.f, mx = -INFINITY;
    for (int n = lo; n < hi; ++n) {
        float v = h2[(long long)n * HDIM + t];
        sum += v;
        mx = fmaxf(mx, v);
    }

    __shared__ float p[2 * HDIM];
    p[t]        = sum / (float)(cnt > 1 ? cnt : 1);
    p[HDIM + t] = (cnt > 0) ? mx : 0.f;
    __syncthreads();

    float acc = bf1[t];
#pragma unroll 8
    for (int k = 0; k < 2 * HDIM; ++k)
        acc += p[k] * Wf1[k * HDIM + t];
    float hval = fmaxf(acc, 0.f);

    float partial = hval * Wf2[t];
    // 64-lane wave reduce then cross-wave via LDS
#pragma unroll
    for (int off = 32; off > 0; off >>= 1)
        partial += __shfl_down(partial, off);
    __shared__ float red[4];
    if ((t & 63) == 0) red[t >> 6] = partial;
    __syncthreads();
    if (t == 0) out[g] = red[0] + red[1] + red[2] + red[3] + bf2[0];
}

// ---------------------------------------------------------------------------
extern "C" void kernel_launch(void* const* d_in, const int* in_sizes, int n_in,
                              void* d_out, int out_size, void* d_ws, size_t ws_size,
                              hipStream_t stream)
{
    const float* x     = (const float*)d_in[0];
    const int*   ei    = (const int*)d_in[1];
    const int*   batch = (const int*)d_in[2];
    const float* W1 = (const float*)d_in[3];
    const float* b1 = (const float*)d_in[4];
    const float* W2 = (const float*)d_in[5];
    const float* b2 = (const float*)d_in[6];
    const float* W3 = (const float*)d_in[7];
    const float* b3 = (const float*)d_in[8];
    const float* W4 = (const float*)d_in[9];
    const float* b4 = (const float*)d_in[10];
    const float* Wf1 = (const float*)d_in[11];
    const float* bf1 = (const float*)d_in[12];
    const float* Wf2 = (const float*)d_in[13];
    const float* bf2 = (const float*)d_in[14];
    float* out = (float*)d_out;

    const int N  = in_sizes[0] / D_IN;   // 50000
    const int E  = in_sizes[1] / 2;      // 600000
    const int Gn = out_size;             // 128

    // workspace: three N*256 f32 buffers (A, B, C) = 153.6 MB
    float* A = (float*)d_ws;
    float* B = A + (size_t)N * HDIM;
    float* C = B + (size_t)N * HDIM;

    const int gblocks = (N + 63) / 64;

    // conv1: agg1 (in C, N*128) = scatter(x); t1(A); h1(B)
    zero_kernel<<<2048, 256, 0, stream>>>((float4*)C, N * D_IN / 4);
    {
        int threads = E * (D_IN / 4);
        scatter_add_kernel<5><<<(threads + 255) / 256, 256, 0, stream>>>(x, ei, C, E);
    }
    gemm_relu_kernel<128, true ><<<gblocks, 256, 0, stream>>>(x, C, W1, b1, A, N);
    gemm_relu_kernel<256, false><<<gblocks, 256, 0, stream>>>(A, nullptr, W2, b2, B, N);

    // conv2: agg2 (in A) = scatter(h1=B); t2(C); h2(B2->B? write to C then B)
    zero_kernel<<<2048, 256, 0, stream>>>((float4*)A, N * HDIM / 4);
    {
        int threads = E * (HDIM / 4);
        scatter_add_kernel<6><<<(threads + 255) / 256, 256, 0, stream>>>(B, ei, A, E);
    }
    gemm_relu_kernel<256, true ><<<gblocks, 256, 0, stream>>>(B, A, W3, b3, C, N);
    gemm_relu_kernel<256, false><<<gblocks, 256, 0, stream>>>(C, nullptr, W4, b4, B, N);

    // pooling + final MLP
    pool_mlp_kernel<<<Gn, 256, 0, stream>>>(B, batch, Wf1, bf1, Wf2, bf2, out, N);
}

// Round 3
// 2044.138 us; speedup vs baseline: 2.3655x; 2.3655x over previous
//
#include <hip/hip_runtime.h>
#include <math.h>

#define D_IN 128
#define HDIM 256

// ---------------------------------------------------------------------------
// zero an int buffer (grid-stride)
// ---------------------------------------------------------------------------
__global__ __launch_bounds__(256) void zero_int_kernel(int* __restrict__ p, int n) {
    int i = blockIdx.x * 256 + threadIdx.x;
    int stride = gridDim.x * 256;
    for (; i < n; i += stride) p[i] = 0;
}

// ---------------------------------------------------------------------------
// CSR build step 1: histogram of dst degrees
// ---------------------------------------------------------------------------
__global__ __launch_bounds__(256) void hist_kernel(
    const int* __restrict__ ei, int* __restrict__ deg, int E)
{
    int e = blockIdx.x * 256 + threadIdx.x;
    if (e < E) atomicAdd(&deg[ei[E + e]], 1);
}

// ---------------------------------------------------------------------------
// CSR build step 2: single-block exclusive scan of deg[N] -> rowptr / cursor
// ---------------------------------------------------------------------------
__global__ __launch_bounds__(1024) void scan_kernel(
    int* __restrict__ cursor /* in: deg, out: start offsets */,
    int* __restrict__ rowptr, int N)
{
    __shared__ int part[1024];
    const int t = threadIdx.x;
    const int per = (N + 1023) / 1024;
    const int lo = t * per;
    const int hi = (lo + per < N) ? lo + per : N;

    int s = 0;
    for (int i = lo; i < hi; ++i) s += cursor[i];
    part[t] = s;
    __syncthreads();

    for (int off = 1; off < 1024; off <<= 1) {
        int v = (t >= off) ? part[t - off] : 0;
        __syncthreads();
        part[t] += v;
        __syncthreads();
    }
    int run = part[t] - s;   // exclusive prefix for this chunk

    for (int i = lo; i < hi; ++i) {
        int d = cursor[i];
        rowptr[i] = run;
        cursor[i] = run;
        run += d;
    }
    if (hi == N && lo < N) rowptr[N] = run;   // total == E
}

// ---------------------------------------------------------------------------
// CSR build step 3: fill per-dst src lists
// ---------------------------------------------------------------------------
__global__ __launch_bounds__(256) void fill_kernel(
    const int* __restrict__ ei, int* __restrict__ cursor,
    int* __restrict__ srclist, int E)
{
    int e = blockIdx.x * 256 + threadIdx.x;
    if (e < E) {
        int s = ei[e];
        int d = ei[E + e];
        int pos = atomicAdd(&cursor[d], 1);
        srclist[pos] = s;
    }
}

// ---------------------------------------------------------------------------
// gather-aggregate with fused self term: z[v] = feat[v] + sum_{u->v} feat[u]
// one 64-lane wave per node; D=256: float4/lane (1KB row), D=128: float2/lane
// (512B row). Neighbor loop unrolled x4 with index prefetch for MLP.
// ---------------------------------------------------------------------------
template<int D>
__global__ __launch_bounds__(256) void gather_agg_kernel(
    const float* __restrict__ feat, const int* __restrict__ rowptr,
    const int* __restrict__ srclist, float* __restrict__ z, int N)
{
    const int wave = (blockIdx.x * 256 + threadIdx.x) >> 6;
    const int lane = threadIdx.x & 63;
    if (wave >= N) return;
    const int lo = rowptr[wave];
    const int hi = rowptr[wave + 1];

    if (D == 256) {
        const int c = lane * 4;
        float4 acc = *(const float4*)(feat + (size_t)wave * D + c);  // self
        int i = lo;
        for (; i + 4 <= hi; i += 4) {
            int s0 = srclist[i + 0], s1 = srclist[i + 1];
            int s2 = srclist[i + 2], s3 = srclist[i + 3];
            float4 v0 = *(const float4*)(feat + (size_t)s0 * D + c);
            float4 v1 = *(const float4*)(feat + (size_t)s1 * D + c);
            float4 v2 = *(const float4*)(feat + (size_t)s2 * D + c);
            float4 v3 = *(const float4*)(feat + (size_t)s3 * D + c);
            acc.x += v0.x + v1.x + v2.x + v3.x;
            acc.y += v0.y + v1.y + v2.y + v3.y;
            acc.z += v0.z + v1.z + v2.z + v3.z;
            acc.w += v0.w + v1.w + v2.w + v3.w;
        }
        for (; i < hi; ++i) {
            int s = srclist[i];
            float4 v = *(const float4*)(feat + (size_t)s * D + c);
            acc.x += v.x; acc.y += v.y; acc.z += v.z; acc.w += v.w;
        }
        *(float4*)(z + (size_t)wave * D + c) = acc;
    } else {
        const int c = lane * 2;
        float2 acc = *(const float2*)(feat + (size_t)wave * D + c);  // self
        int i = lo;
        for (; i + 4 <= hi; i += 4) {
            int s0 = srclist[i + 0], s1 = srclist[i + 1];
            int s2 = srclist[i + 2], s3 = srclist[i + 3];
            float2 v0 = *(const float2*)(feat + (size_t)s0 * D + c);
            float2 v1 = *(const float2*)(feat + (size_t)s1 * D + c);
            float2 v2 = *(const float2*)(feat + (size_t)s2 * D + c);
            float2 v3 = *(const float2*)(feat + (size_t)s3 * D + c);
            acc.x += v0.x + v1.x + v2.x + v3.x;
            acc.y += v0.y + v1.y + v2.y + v3.y;
        }
        for (; i < hi; ++i) {
            int s = srclist[i];
            float2 v = *(const float2*)(feat + (size_t)s * D + c);
            acc.x += v.x; acc.y += v.y;
        }
        *(float2*)(z + (size_t)wave * D + c) = acc;
    }
}

// ---------------------------------------------------------------------------
// OUT[r][c] = relu( X[r] @ W + Bias )   X:[N][K]  W:[K][256]
// BM=64, BN=256 (full), BK=32. 256 threads: 64 col-groups x 4 row-groups,
// each thread owns 16 rows x 4 cols. LDS: A 8KB + W 32KB.
// ---------------------------------------------------------------------------
template<int K>
__global__ __launch_bounds__(256) void gemm_relu_kernel(
    const float* __restrict__ X, const float* __restrict__ W,
    const float* __restrict__ Bias, float* __restrict__ OUT, int Nrows)
{
    __shared__ float As[64][32];
    __shared__ float Ws[32][256];
    const int t    = threadIdx.x;
    const int row0 = blockIdx.x * 64;
    const int tx   = t & 63;
    const int ty   = t >> 6;          // wave-uniform
    const int col0 = tx * 4;

    float acc[16][4];
#pragma unroll
    for (int i = 0; i < 16; ++i)
#pragma unroll
        for (int j = 0; j < 4; ++j) acc[i][j] = 0.f;

    for (int k0 = 0; k0 < K; k0 += 32) {
#pragma unroll
        for (int i = 0; i < 2; ++i) {
            int idx = t + i * 256;
            int r = idx >> 3;
            int c = (idx & 7) << 2;
            int grow = row0 + r;
            float4 v = make_float4(0.f, 0.f, 0.f, 0.f);
            if (grow < Nrows)
                v = *(const float4*)(X + (long long)grow * K + k0 + c);
            *(float4*)&As[r][c] = v;
        }
#pragma unroll
        for (int i = 0; i < 8; ++i) {
            int idx = t + i * 256;
            int kk = idx >> 6;
            int c = (idx & 63) << 2;
            *(float4*)&Ws[kk][c] = *(const float4*)(W + (long long)(k0 + kk) * HDIM + c);
        }
        __syncthreads();

#pragma unroll
        for (int kk4 = 0; kk4 < 8; ++kk4) {
            float4 w0 = *(const float4*)&Ws[kk4 * 4 + 0][col0];
            float4 w1 = *(const float4*)&Ws[kk4 * 4 + 1][col0];
            float4 w2 = *(const float4*)&Ws[kk4 * 4 + 2][col0];
            float4 w3 = *(const float4*)&Ws[kk4 * 4 + 3][col0];
#pragma unroll
            for (int i = 0; i < 16; ++i) {
                float4 a = *(const float4*)&As[ty * 16 + i][kk4 * 4];  // wave-uniform broadcast
                acc[i][0] += a.x * w0.x + a.y * w1.x + a.z * w2.x + a.w * w3.x;
                acc[i][1] += a.x * w0.y + a.y * w1.y + a.z * w2.y + a.w * w3.y;
                acc[i][2] += a.x * w0.z + a.y * w1.z + a.z * w2.z + a.w * w3.z;
                acc[i][3] += a.x * w0.w + a.y * w1.w + a.z * w2.w + a.w * w3.w;
            }
        }
        __syncthreads();
    }

    float4 b4 = *(const float4*)(Bias + col0);
#pragma unroll
    for (int i = 0; i < 16; ++i) {
        int grow = row0 + ty * 16 + i;
        if (grow < Nrows) {
            float4 o;
            o.x = fmaxf(acc[i][0] + b4.x, 0.f);
            o.y = fmaxf(acc[i][1] + b4.y, 0.f);
            o.z = fmaxf(acc[i][2] + b4.z, 0.f);
            o.w = fmaxf(acc[i][3] + b4.w, 0.f);
            *(float4*)(OUT + (long long)grow * HDIM + col0) = o;
        }
    }
}

// ---------------------------------------------------------------------------
// one block (256 thr) per graph: mean/max pool over [lo,hi) then 2-layer MLP
// ---------------------------------------------------------------------------
__global__ __launch_bounds__(256) void pool_mlp_kernel(
    const float* __restrict__ h2, const int* __restrict__ batch,
    const float* __restrict__ Wf1, const float* __restrict__ bf1,
    const float* __restrict__ Wf2, const float* __restrict__ bf2,
    float* __restrict__ out, int N)
{
    const int g = blockIdx.x;
    const int t = threadIdx.x;

    __shared__ int s_bounds[2];
    if (t < 2) {
        int target = g + t;
        int lo = 0, hi = N;
        while (lo < hi) {
            int mid = (lo + hi) >> 1;
            if (batch[mid] < target) lo = mid + 1; else hi = mid;
        }
        s_bounds[t] = lo;
    }
    __syncthreads();
    const int lo = s_bounds[0], hi = s_bounds[1];
    const int cnt = hi - lo;

    float sum = 0.f, mx = -INFINITY;
    for (int n = lo; n < hi; ++n) {
        float v = h2[(long long)n * HDIM + t];
        sum += v;
        mx = fmaxf(mx, v);
    }

    __shared__ float p[2 * HDIM];
    p[t]        = sum / (float)(cnt > 1 ? cnt : 1);
    p[HDIM + t] = (cnt > 0) ? mx : 0.f;
    __syncthreads();

    float acc = bf1[t];
#pragma unroll 8
    for (int k = 0; k < 2 * HDIM; ++k)
        acc += p[k] * Wf1[k * HDIM + t];
    float hval = fmaxf(acc, 0.f);

    float partial = hval * Wf2[t];
#pragma unroll
    for (int off = 32; off > 0; off >>= 1)
        partial += __shfl_down(partial, off);
    __shared__ float red[4];
    if ((t & 63) == 0) red[t >> 6] = partial;
    __syncthreads();
    if (t == 0) out[g] = red[0] + red[1] + red[2] + red[3] + bf2[0];
}

// ---------------------------------------------------------------------------
extern "C" void kernel_launch(void* const* d_in, const int* in_sizes, int n_in,
                              void* d_out, int out_size, void* d_ws, size_t ws_size,
                              hipStream_t stream)
{
    const float* x     = (const float*)d_in[0];
    const int*   ei    = (const int*)d_in[1];
    const int*   batch = (const int*)d_in[2];
    const float* W1 = (const float*)d_in[3];
    const float* b1 = (const float*)d_in[4];
    const float* W2 = (const float*)d_in[5];
    const float* b2 = (const float*)d_in[6];
    const float* W3 = (const float*)d_in[7];
    const float* b3 = (const float*)d_in[8];
    const float* W4 = (const float*)d_in[9];
    const float* b4 = (const float*)d_in[10];
    const float* Wf1 = (const float*)d_in[11];
    const float* bf1 = (const float*)d_in[12];
    const float* Wf2 = (const float*)d_in[13];
    const float* bf2 = (const float*)d_in[14];
    float* out = (float*)d_out;

    const int N  = in_sizes[0] / D_IN;   // 50000
    const int E  = in_sizes[1] / 2;      // 600000
    const int Gn = out_size;             // 128

    // workspace layout: 2x N*256 f32 ping-pong buffers + CSR arrays (~105 MB)
    float* P0 = (float*)d_ws;
    float* P1 = P0 + (size_t)N * HDIM;
    int* rowptr  = (int*)(P1 + (size_t)N * HDIM);
    int* cursor  = rowptr + (N + 1);
    int* srclist = cursor + N;

    const int gblocks  = (N + 63) / 64;        // GEMM grid
    const int eblocks  = (E + 255) / 256;      // per-edge grid
    const int wblocks  = (N + 3) / 4;          // 4 waves/block, 1 wave/node

    // ---- CSR build (dst-sorted adjacency), used by both convs ----
    zero_int_kernel<<<64, 256, 0, stream>>>(cursor, N);
    hist_kernel<<<eblocks, 256, 0, stream>>>(ei, cursor, E);
    scan_kernel<<<1, 1024, 0, stream>>>(cursor, rowptr, N);
    fill_kernel<<<eblocks, 256, 0, stream>>>(ei, cursor, srclist, E);

    // ---- conv1: z1 = x + agg(x)  [N,128] -> t1 -> h1 ----
    gather_agg_kernel<128><<<wblocks, 256, 0, stream>>>(x, rowptr, srclist, P0, N);
    gemm_relu_kernel<128><<<gblocks, 256, 0, stream>>>(P0, W1, b1, P1, N);   // t1
    gemm_relu_kernel<256><<<gblocks, 256, 0, stream>>>(P1, W2, b2, P0, N);   // h1

    // ---- conv2: z2 = h1 + agg(h1) [N,256] -> t2 -> h2 ----
    gather_agg_kernel<256><<<wblocks, 256, 0, stream>>>(P0, rowptr, srclist, P1, N);
    gemm_relu_kernel<256><<<gblocks, 256, 0, stream>>>(P1, W3, b3, P0, N);   // t2
    gemm_relu_kernel<256><<<gblocks, 256, 0, stream>>>(P0, W4, b4, P1, N);   // h2

    // ---- pooling + final MLP ----
    pool_mlp_kernel<<<Gn, 256, 0, stream>>>(P1, batch, Wf1, bf1, Wf2, bf2, out, N);
}

// Round 6
// 730.861 us; speedup vs baseline: 6.6161x; 2.7969x over previous
//
#include <hip/hip_runtime.h>
#include <math.h>

#define D_IN 128
#define HDIM 256

typedef __attribute__((ext_vector_type(8))) short bf16x8;
typedef __attribute__((ext_vector_type(4))) float f32x4;

// ---------------- bf16 helpers (RNE) ----------------
__device__ inline ushort f2bf(float v) {
    union { float f; unsigned u; } c; c.f = v;
    unsigned u = c.u;
    return (ushort)((u + 0x7FFFu + ((u >> 16) & 1u)) >> 16);
}
__device__ inline float bf2f(ushort h) {
    union { unsigned u; float f; } c; c.u = ((unsigned)h) << 16; return c.f;
}
__device__ inline float bflo(unsigned u) {  // low ushort of packed pair -> float
    union { unsigned u; float f; } c; c.u = u << 16; return c.f;
}
__device__ inline float bfhi(unsigned u) {  // high ushort of packed pair -> float
    union { unsigned u; float f; } c; c.u = u & 0xFFFF0000u; return c.f;
}

// ---------------------------------------------------------------------------
// zero an int buffer (grid-stride)
// ---------------------------------------------------------------------------
__global__ __launch_bounds__(256) void zero_int_kernel(int* __restrict__ p, int n) {
    int i = blockIdx.x * 256 + threadIdx.x;
    int stride = gridDim.x * 256;
    for (; i < n; i += stride) p[i] = 0;
}

// ---------------------------------------------------------------------------
// CSR build: histogram -> scan -> fill
// ---------------------------------------------------------------------------
__global__ __launch_bounds__(256) void hist_kernel(
    const int* __restrict__ ei, int* __restrict__ deg, int E)
{
    int e = blockIdx.x * 256 + threadIdx.x;
    if (e < E) atomicAdd(&deg[ei[E + e]], 1);
}

__global__ __launch_bounds__(1024) void scan_kernel(
    int* __restrict__ cursor, int* __restrict__ rowptr, int N)
{
    __shared__ int part[1024];
    const int t = threadIdx.x;
    const int per = (N + 1023) / 1024;
    const int lo = t * per;
    const int hi = (lo + per < N) ? lo + per : N;

    int s = 0;
    for (int i = lo; i < hi; ++i) s += cursor[i];
    part[t] = s;
    __syncthreads();
    for (int off = 1; off < 1024; off <<= 1) {
        int v = (t >= off) ? part[t - off] : 0;
        __syncthreads();
        part[t] += v;
        __syncthreads();
    }
    int run = part[t] - s;
    for (int i = lo; i < hi; ++i) {
        int d = cursor[i];
        rowptr[i] = run;
        cursor[i] = run;
        run += d;
    }
    if (hi == N && lo < N) rowptr[N] = run;
}

__global__ __launch_bounds__(256) void fill_kernel(
    const int* __restrict__ ei, int* __restrict__ cursor,
    int* __restrict__ srclist, int E)
{
    int e = blockIdx.x * 256 + threadIdx.x;
    if (e < E) {
        int s = ei[e];
        int d = ei[E + e];
        int pos = atomicAdd(&cursor[d], 1);
        srclist[pos] = s;
    }
}

// ---------------------------------------------------------------------------
// weight split + transpose:  W[K][256] fp32  ->  Wt_hi/Wt_lo [256][K] bf16
// ---------------------------------------------------------------------------
template<int K>
__global__ __launch_bounds__(256) void wsplit_kernel(
    const float* __restrict__ W, ushort* __restrict__ Wthi, ushort* __restrict__ Wtlo)
{
    int idx = blockIdx.x * 256 + threadIdx.x;
    if (idx >= K * 256) return;
    int k = idx >> 8;
    int c = idx & 255;
    float v = W[idx];
    ushort h = f2bf(v);
    Wthi[c * K + k] = h;
    Wtlo[c * K + k] = f2bf(v - bf2f(h));
}

// ---------------------------------------------------------------------------
// gather1: z1[v] = x[v] + sum x[u]   (fp32 in, split-bf16 out)  D=128
// one 64-lane wave per node, 2 cols/lane
// ---------------------------------------------------------------------------
__global__ __launch_bounds__(256) void gather1_kernel(
    const float* __restrict__ feat, const int* __restrict__ rowptr,
    const int* __restrict__ srclist, ushort* __restrict__ Zhi,
    ushort* __restrict__ Zlo, int N)
{
    const int wave = (blockIdx.x * 256 + threadIdx.x) >> 6;
    const int lane = threadIdx.x & 63;
    if (wave >= N) return;
    const int lo_ = rowptr[wave], hi_ = rowptr[wave + 1];
    const int c = lane * 2;
    float2 acc = *(const float2*)(feat + (size_t)wave * D_IN + c);
    int i = lo_;
    for (; i + 4 <= hi_; i += 4) {
        int s0 = srclist[i + 0], s1 = srclist[i + 1];
        int s2 = srclist[i + 2], s3 = srclist[i + 3];
        float2 v0 = *(const float2*)(feat + (size_t)s0 * D_IN + c);
        float2 v1 = *(const float2*)(feat + (size_t)s1 * D_IN + c);
        float2 v2 = *(const float2*)(feat + (size_t)s2 * D_IN + c);
        float2 v3 = *(const float2*)(feat + (size_t)s3 * D_IN + c);
        acc.x += v0.x + v1.x + v2.x + v3.x;
        acc.y += v0.y + v1.y + v2.y + v3.y;
    }
    for (; i < hi_; ++i) {
        int s = srclist[i];
        float2 v = *(const float2*)(feat + (size_t)s * D_IN + c);
        acc.x += v.x; acc.y += v.y;
    }
    ushort h0 = f2bf(acc.x), h1 = f2bf(acc.y);
    ushort l0 = f2bf(acc.x - bf2f(h0)), l1 = f2bf(acc.y - bf2f(h1));
    size_t o = ((size_t)wave * D_IN + c) >> 1;   // packed uint index
    ((unsigned*)Zhi)[o] = (unsigned)h0 | ((unsigned)h1 << 16);
    ((unsigned*)Zlo)[o] = (unsigned)l0 | ((unsigned)l1 << 16);
}

// ---------------------------------------------------------------------------
// gather2: z2[v] = h1[v] + sum h1[u]  (split-bf16 in & out)  D=256
// one wave per node, 4 cols/lane
// ---------------------------------------------------------------------------
__global__ __launch_bounds__(256) void gather2_kernel(
    const ushort* __restrict__ Fhi, const ushort* __restrict__ Flo,
    const int* __restrict__ rowptr, const int* __restrict__ srclist,
    ushort* __restrict__ Zhi, ushort* __restrict__ Zlo, int N)
{
    const int wave = (blockIdx.x * 256 + threadIdx.x) >> 6;
    const int lane = threadIdx.x & 63;
    if (wave >= N) return;
    const int lo_ = rowptr[wave], hi_ = rowptr[wave + 1];
    const int c = lane * 4;
    const size_t sbase = (size_t)wave * HDIM + c;
    uint2 sh = *(const uint2*)(Fhi + sbase);
    uint2 sl = *(const uint2*)(Flo + sbase);
    float a0 = bflo(sh.x) + bflo(sl.x);
    float a1 = bfhi(sh.x) + bfhi(sl.x);
    float a2 = bflo(sh.y) + bflo(sl.y);
    float a3 = bfhi(sh.y) + bfhi(sl.y);
    int i = lo_;
    for (; i + 2 <= hi_; i += 2) {
        int s0 = srclist[i], s1 = srclist[i + 1];
        uint2 h0 = *(const uint2*)(Fhi + (size_t)s0 * HDIM + c);
        uint2 l0 = *(const uint2*)(Flo + (size_t)s0 * HDIM + c);
        uint2 h1 = *(const uint2*)(Fhi + (size_t)s1 * HDIM + c);
        uint2 l1 = *(const uint2*)(Flo + (size_t)s1 * HDIM + c);
        a0 += bflo(h0.x) + bflo(l0.x) + bflo(h1.x) + bflo(l1.x);
        a1 += bfhi(h0.x) + bfhi(l0.x) + bfhi(h1.x) + bfhi(l1.x);
        a2 += bflo(h0.y) + bflo(l0.y) + bflo(h1.y) + bflo(l1.y);
        a3 += bfhi(h0.y) + bfhi(l0.y) + bfhi(h1.y) + bfhi(l1.y);
    }
    for (; i < hi_; ++i) {
        int s = srclist[i];
        uint2 vh = *(const uint2*)(Fhi + (size_t)s * HDIM + c);
        uint2 vl = *(const uint2*)(Flo + (size_t)s * HDIM + c);
        a0 += bflo(vh.x) + bflo(vl.x);
        a1 += bfhi(vh.x) + bfhi(vl.x);
        a2 += bflo(vh.y) + bflo(vl.y);
        a3 += bfhi(vh.y) + bfhi(vl.y);
    }
    ushort h0 = f2bf(a0), h1 = f2bf(a1), h2 = f2bf(a2), h3 = f2bf(a3);
    ushort l0 = f2bf(a0 - bf2f(h0)), l1 = f2bf(a1 - bf2f(h1));
    ushort l2 = f2bf(a2 - bf2f(h2)), l3 = f2bf(a3 - bf2f(h3));
    uint2 oh, ol;
    oh.x = (unsigned)h0 | ((unsigned)h1 << 16); oh.y = (unsigned)h2 | ((unsigned)h3 << 16);
    ol.x = (unsigned)l0 | ((unsigned)l1 << 16); ol.y = (unsigned)l2 | ((unsigned)l3 << 16);
    *(uint2*)(Zhi + sbase) = oh;
    *(uint2*)(Zlo + sbase) = ol;
}

// ---------------------------------------------------------------------------
// split-bf16 MFMA GEMM:  OUT[r][c] = relu( A[r] @ W + Bias )
// A = Ahi+Alo [N][K] bf16, W given transposed+split: Bt_hi/lo [256][K] bf16.
// BM=64, BN=256, BK=32. 256 thr = 4 waves, each wave -> 64x64 tile
// (4x4 fragments of 16x16, mfma_f32_16x16x32_bf16, 3 mfma per fragment pair).
// LDS rows padded to 40 ushorts (80B) -> ~2-way bank conflicts (free).
// ---------------------------------------------------------------------------
template<int K, bool SPLIT_OUT>
__global__ __launch_bounds__(256) void mfma_gemm_kernel(
    const ushort* __restrict__ Ahi, const ushort* __restrict__ Alo,
    const ushort* __restrict__ Bthi, const ushort* __restrict__ Btlo,
    const float* __restrict__ Bias, float* __restrict__ OUTf,
    ushort* __restrict__ OUThi, ushort* __restrict__ OUTlo, int Nrows)
{
    __shared__ ushort As[2][64][40];
    __shared__ ushort Ws[2][256][40];
    const int t    = threadIdx.x;
    const int wv   = t >> 6;
    const int lane = t & 63;
    const int l15  = lane & 15;
    const int l4   = lane >> 4;
    const int row0 = blockIdx.x * 64;
    const int wc0  = wv * 64;

    f32x4 acc[4][4];
#pragma unroll
    for (int m = 0; m < 4; ++m)
#pragma unroll
        for (int n = 0; n < 4; ++n) acc[m][n] = (f32x4){0.f, 0.f, 0.f, 0.f};

    const int ar = t >> 2;             // A row within tile
    const int as = (t & 3) * 8;        // A k-segment within tile
    const int grow = min(row0 + ar, Nrows - 1);
    const size_t abase = (size_t)grow * K + as;

    for (int k0 = 0; k0 < K; k0 += 32) {
        // stage A (hi/lo): one 16B seg each per thread
        *(uint4*)&As[0][ar][as] = *(const uint4*)(Ahi + abase + k0);
        *(uint4*)&As[1][ar][as] = *(const uint4*)(Alo + abase + k0);
        // stage W^T (hi/lo): 4 segs each per thread
#pragma unroll
        for (int i = 0; i < 4; ++i) {
            int sid = t + i * 256;
            int wc  = sid >> 2;
            int wsg = (sid & 3) * 8;
            size_t wb = (size_t)wc * K + k0 + wsg;
            *(uint4*)&Ws[0][wc][wsg] = *(const uint4*)(Bthi + wb);
            *(uint4*)&Ws[1][wc][wsg] = *(const uint4*)(Btlo + wb);
        }
        __syncthreads();

        bf16x8 ah[4], al[4], bh[4], bl[4];
#pragma unroll
        for (int m = 0; m < 4; ++m) {
            ah[m] = *(const bf16x8*)&As[0][m * 16 + l15][l4 * 8];
            al[m] = *(const bf16x8*)&As[1][m * 16 + l15][l4 * 8];
        }
#pragma unroll
        for (int n = 0; n < 4; ++n) {
            bh[n] = *(const bf16x8*)&Ws[0][wc0 + n * 16 + l15][l4 * 8];
            bl[n] = *(const bf16x8*)&Ws[1][wc0 + n * 16 + l15][l4 * 8];
        }
#pragma unroll
        for (int m = 0; m < 4; ++m)
#pragma unroll
            for (int n = 0; n < 4; ++n) {
                acc[m][n] = __builtin_amdgcn_mfma_f32_16x16x32_bf16(ah[m], bh[n], acc[m][n], 0, 0, 0);
                acc[m][n] = __builtin_amdgcn_mfma_f32_16x16x32_bf16(ah[m], bl[n], acc[m][n], 0, 0, 0);
                acc[m][n] = __builtin_amdgcn_mfma_f32_16x16x32_bf16(al[m], bh[n], acc[m][n], 0, 0, 0);
            }
        __syncthreads();
    }

    // epilogue: C/D layout col=lane&15, row=(lane>>4)*4+reg (HW-verified)
#pragma unroll
    for (int n = 0; n < 4; ++n) {
        const int ocol = wc0 + n * 16 + l15;
        const float bs = Bias[ocol];
#pragma unroll
        for (int m = 0; m < 4; ++m) {
#pragma unroll
            for (int r = 0; r < 4; ++r) {
                int orow = row0 + m * 16 + l4 * 4 + r;
                if (orow < Nrows) {
                    float v = fmaxf(acc[m][n][r] + bs, 0.f);
                    size_t o = (size_t)orow * HDIM + ocol;
                    if (SPLIT_OUT) {
                        ushort h = f2bf(v);
                        OUThi[o] = h;
                        OUTlo[o] = f2bf(v - bf2f(h));
                    } else {
                        OUTf[o] = v;
                    }
                }
            }
        }
    }
}

// ---------------------------------------------------------------------------
// one block (256 thr) per graph: mean/max pool then 2-layer MLP (fp32 h2)
// ---------------------------------------------------------------------------
__global__ __launch_bounds__(256) void pool_mlp_kernel(
    const float* __restrict__ h2, const int* __restrict__ batch,
    const float* __restrict__ Wf1, const float* __restrict__ bf1,
    const float* __restrict__ Wf2, const float* __restrict__ bf2,
    float* __restrict__ out, int N)
{
    const int g = blockIdx.x;
    const int t = threadIdx.x;

    __shared__ int s_bounds[2];
    if (t < 2) {
        int target = g + t;
        int lo = 0, hi = N;
        while (lo < hi) {
            int mid = (lo + hi) >> 1;
            if (batch[mid] < target) lo = mid + 1; else hi = mid;
        }
        s_bounds[t] = lo;
    }
    __syncthreads();
    const int lo = s_bounds[0], hi = s_bounds[1];
    const int cnt = hi - lo;

    float sum = 0.f, mx = -INFINITY;
    for (int n = lo; n < hi; ++n) {
        float v = h2[(long long)n * HDIM + t];
        sum += v;
        mx = fmaxf(mx, v);
    }

    __shared__ float p[2 * HDIM];
    p[t]        = sum / (float)(cnt > 1 ? cnt : 1);
    p[HDIM + t] = (cnt > 0) ? mx : 0.f;
    __syncthreads();

    float acc = bf1[t];
#pragma unroll 8
    for (int k = 0; k < 2 * HDIM; ++k)
        acc += p[k] * Wf1[k * HDIM + t];
    float hval = fmaxf(acc, 0.f);

    float partial = hval * Wf2[t];
#pragma unroll
    for (int off = 32; off > 0; off >>= 1)
        partial += __shfl_down(partial, off);
    __shared__ float red[4];
    if ((t & 63) == 0) red[t >> 6] = partial;
    __syncthreads();
    if (t == 0) out[g] = red[0] + red[1] + red[2] + red[3] + bf2[0];
}

// ---------------------------------------------------------------------------
extern "C" void kernel_launch(void* const* d_in, const int* in_sizes, int n_in,
                              void* d_out, int out_size, void* d_ws, size_t ws_size,
                              hipStream_t stream)
{
    const float* x     = (const float*)d_in[0];
    const int*   ei    = (const int*)d_in[1];
    const int*   batch = (const int*)d_in[2];
    const float* W1 = (const float*)d_in[3];
    const float* b1 = (const float*)d_in[4];
    const float* W2 = (const float*)d_in[5];
    const float* b2 = (const float*)d_in[6];
    const float* W3 = (const float*)d_in[7];
    const float* b3 = (const float*)d_in[8];
    const float* W4 = (const float*)d_in[9];
    const float* b4 = (const float*)d_in[10];
    const float* Wf1 = (const float*)d_in[11];
    const float* bf1 = (const float*)d_in[12];
    const float* Wf2 = (const float*)d_in[13];
    const float* bf2 = (const float*)d_in[14];
    float* out = (float*)d_out;

    const int N  = in_sizes[0] / D_IN;   // 50000
    const int E  = in_sizes[1] / 2;      // 600000
    const int Gn = out_size;             // 128

    // ---- workspace layout ----
    // R0 / R1: two N*256-float regions, ping-pong. Each region also serves as
    // two N*256 bf16 arrays (hi at base, lo at +N*256 ushorts).
    const size_t R = (size_t)N * HDIM;     // floats per region
    float* R0f = (float*)d_ws;
    float* R1f = R0f + R;
    ushort* R0u = (ushort*)R0f;
    ushort* R1u = (ushort*)R1f;

    ushort* wbuf = (ushort*)(R1f + R);
    ushort* W1thi = wbuf;                       // 128*256
    ushort* W1tlo = W1thi + 128 * 256;
    ushort* W2thi = W1tlo + 128 * 256;          // 256*256 each below
    ushort* W2tlo = W2thi + 256 * 256;
    ushort* W3thi = W2tlo + 256 * 256;
    ushort* W3tlo = W3thi + 256 * 256;
    ushort* W4thi = W3tlo + 256 * 256;
    ushort* W4tlo = W4thi + 256 * 256;

    int* rowptr  = (int*)(W4tlo + 256 * 256);
    int* cursor  = rowptr + (N + 1);
    int* srclist = cursor + N;

    const int gblocks = (N + 63) / 64;
    const int eblocks = (E + 255) / 256;
    const int wblocks = (N + 3) / 4;

    // ---- CSR build ----
    zero_int_kernel<<<64, 256, 0, stream>>>(cursor, N);
    hist_kernel<<<eblocks, 256, 0, stream>>>(ei, cursor, E);
    scan_kernel<<<1, 1024, 0, stream>>>(cursor, rowptr, N);
    fill_kernel<<<eblocks, 256, 0, stream>>>(ei, cursor, srclist, E);

    // ---- weight split+transpose ----
    wsplit_kernel<128><<<128, 256, 0, stream>>>(W1, W1thi, W1tlo);
    wsplit_kernel<256><<<256, 256, 0, stream>>>(W2, W2thi, W2tlo);
    wsplit_kernel<256><<<256, 256, 0, stream>>>(W3, W3thi, W3tlo);
    wsplit_kernel<256><<<256, 256, 0, stream>>>(W4, W4thi, W4tlo);

    // bf16 array views within regions
    ushort* Z1hi = R0u;                 ushort* Z1lo = R0u + (size_t)N * D_IN;   // [N][128]
    ushort* T1hi = R1u;                 ushort* T1lo = R1u + R;                  // [N][256]
    ushort* H1hi = R0u;                 ushort* H1lo = R0u + R;
    ushort* Z2hi = R1u;                 ushort* Z2lo = R1u + R;
    ushort* T2hi = R0u;                 ushort* T2lo = R0u + R;
    float*  H2   = R1f;

    // ---- conv1 ----
    gather1_kernel<<<wblocks, 256, 0, stream>>>(x, rowptr, srclist, Z1hi, Z1lo, N);
    mfma_gemm_kernel<128, true><<<gblocks, 256, 0, stream>>>(
        Z1hi, Z1lo, W1thi, W1tlo, b1, nullptr, T1hi, T1lo, N);
    mfma_gemm_kernel<256, true><<<gblocks, 256, 0, stream>>>(
        T1hi, T1lo, W2thi, W2tlo, b2, nullptr, H1hi, H1lo, N);

    // ---- conv2 ----
    gather2_kernel<<<wblocks, 256, 0, stream>>>(H1hi, H1lo, rowptr, srclist, Z2hi, Z2lo, N);
    mfma_gemm_kernel<256, true><<<gblocks, 256, 0, stream>>>(
        Z2hi, Z2lo, W3thi, W3tlo, b3, nullptr, T2hi, T2lo, N);
    mfma_gemm_kernel<256, false><<<gblocks, 256, 0, stream>>>(
        T2hi, T2lo, W4thi, W4tlo, b4, H2, nullptr, nullptr, N);

    // ---- pooling + final MLP ----
    pool_mlp_kernel<<<Gn, 256, 0, stream>>>(H2, batch, Wf1, bf1, Wf2, bf2, out, N);
}

// Round 7
// 639.076 us; speedup vs baseline: 7.5663x; 1.1436x over previous
//
#include <hip/hip_runtime.h>
#include <math.h>

#define D_IN 128
#define HDIM 256
#define PSPLIT 8

typedef __attribute__((ext_vector_type(8))) short bf16x8;
typedef __attribute__((ext_vector_type(4))) float f32x4;

// ---------------- bf16 helpers (RNE) ----------------
__device__ inline ushort f2bf(float v) {
    union { float f; unsigned u; } c; c.f = v;
    unsigned u = c.u;
    return (ushort)((u + 0x7FFFu + ((u >> 16) & 1u)) >> 16);
}
__device__ inline float bf2f(ushort h) {
    union { unsigned u; float f; } c; c.u = ((unsigned)h) << 16; return c.f;
}
__device__ inline float bflo(unsigned u) {
    union { unsigned u; float f; } c; c.u = u << 16; return c.f;
}
__device__ inline float bfhi(unsigned u) {
    union { unsigned u; float f; } c; c.u = u & 0xFFFF0000u; return c.f;
}

// ---------------------------------------------------------------------------
__global__ __launch_bounds__(256) void zero_int_kernel(int* __restrict__ p, int n) {
    int i = blockIdx.x * 256 + threadIdx.x;
    int stride = gridDim.x * 256;
    for (; i < n; i += stride) p[i] = 0;
}

// ---------------------------------------------------------------------------
// CSR build: histogram -> scan -> fill
// ---------------------------------------------------------------------------
__global__ __launch_bounds__(256) void hist_kernel(
    const int* __restrict__ ei, int* __restrict__ deg, int E)
{
    int e = blockIdx.x * 256 + threadIdx.x;
    if (e < E) atomicAdd(&deg[ei[E + e]], 1);
}

__global__ __launch_bounds__(1024) void scan_kernel(
    int* __restrict__ cursor, int* __restrict__ rowptr, int N)
{
    __shared__ int part[1024];
    const int t = threadIdx.x;
    const int per = (N + 1023) / 1024;
    const int lo = t * per;
    const int hi = (lo + per < N) ? lo + per : N;

    int s = 0;
    for (int i = lo; i < hi; ++i) s += cursor[i];
    part[t] = s;
    __syncthreads();
    for (int off = 1; off < 1024; off <<= 1) {
        int v = (t >= off) ? part[t - off] : 0;
        __syncthreads();
        part[t] += v;
        __syncthreads();
    }
    int run = part[t] - s;
    for (int i = lo; i < hi; ++i) {
        int d = cursor[i];
        rowptr[i] = run;
        cursor[i] = run;
        run += d;
    }
    if (hi == N && lo < N) rowptr[N] = run;
}

__global__ __launch_bounds__(256) void fill_kernel(
    const int* __restrict__ ei, int* __restrict__ cursor,
    int* __restrict__ srclist, int E)
{
    int e = blockIdx.x * 256 + threadIdx.x;
    if (e < E) {
        int s = ei[e];
        int d = ei[E + e];
        int pos = atomicAdd(&cursor[d], 1);
        srclist[pos] = s;
    }
}

// ---------------------------------------------------------------------------
// weight split + transpose:  W[K][256] fp32  ->  Wt_hi/Wt_lo [256][K] bf16
// ---------------------------------------------------------------------------
template<int K>
__global__ __launch_bounds__(256) void wsplit_kernel(
    const float* __restrict__ W, ushort* __restrict__ Wthi, ushort* __restrict__ Wtlo)
{
    int idx = blockIdx.x * 256 + threadIdx.x;
    if (idx >= K * 256) return;
    int k = idx >> 8;
    int c = idx & 255;
    float v = W[idx];
    ushort h = f2bf(v);
    Wthi[c * K + k] = h;
    Wtlo[c * K + k] = f2bf(v - bf2f(h));
}

// ---------------------------------------------------------------------------
// gather1: z1[v] = x[v] + sum x[u]   (fp32 in, split-bf16 out)  D=128
// ---------------------------------------------------------------------------
__global__ __launch_bounds__(256) void gather1_kernel(
    const float* __restrict__ feat, const int* __restrict__ rowptr,
    const int* __restrict__ srclist, ushort* __restrict__ Zhi,
    ushort* __restrict__ Zlo, int N)
{
    const int wave = (blockIdx.x * 256 + threadIdx.x) >> 6;
    const int lane = threadIdx.x & 63;
    if (wave >= N) return;
    const int lo_ = rowptr[wave], hi_ = rowptr[wave + 1];
    const int c = lane * 2;
    float2 acc = *(const float2*)(feat + (size_t)wave * D_IN + c);
    int i = lo_;
    for (; i + 4 <= hi_; i += 4) {
        int s0 = srclist[i + 0], s1 = srclist[i + 1];
        int s2 = srclist[i + 2], s3 = srclist[i + 3];
        float2 v0 = *(const float2*)(feat + (size_t)s0 * D_IN + c);
        float2 v1 = *(const float2*)(feat + (size_t)s1 * D_IN + c);
        float2 v2 = *(const float2*)(feat + (size_t)s2 * D_IN + c);
        float2 v3 = *(const float2*)(feat + (size_t)s3 * D_IN + c);
        acc.x += v0.x + v1.x + v2.x + v3.x;
        acc.y += v0.y + v1.y + v2.y + v3.y;
    }
    for (; i < hi_; ++i) {
        int s = srclist[i];
        float2 v = *(const float2*)(feat + (size_t)s * D_IN + c);
        acc.x += v.x; acc.y += v.y;
    }
    ushort h0 = f2bf(acc.x), h1 = f2bf(acc.y);
    ushort l0 = f2bf(acc.x - bf2f(h0)), l1 = f2bf(acc.y - bf2f(h1));
    size_t o = ((size_t)wave * D_IN + c) >> 1;
    ((unsigned*)Zhi)[o] = (unsigned)h0 | ((unsigned)h1 << 16);
    ((unsigned*)Zlo)[o] = (unsigned)l0 | ((unsigned)l1 << 16);
}

// ---------------------------------------------------------------------------
// gather2: z2[v] = h1[v] + sum h1[u]  (split-bf16 in & out)  D=256
// ---------------------------------------------------------------------------
__global__ __launch_bounds__(256) void gather2_kernel(
    const ushort* __restrict__ Fhi, const ushort* __restrict__ Flo,
    const int* __restrict__ rowptr, const int* __restrict__ srclist,
    ushort* __restrict__ Zhi, ushort* __restrict__ Zlo, int N)
{
    const int wave = (blockIdx.x * 256 + threadIdx.x) >> 6;
    const int lane = threadIdx.x & 63;
    if (wave >= N) return;
    const int lo_ = rowptr[wave], hi_ = rowptr[wave + 1];
    const int c = lane * 4;
    const size_t sbase = (size_t)wave * HDIM + c;
    uint2 sh = *(const uint2*)(Fhi + sbase);
    uint2 sl = *(const uint2*)(Flo + sbase);
    float a0 = bflo(sh.x) + bflo(sl.x);
    float a1 = bfhi(sh.x) + bfhi(sl.x);
    float a2 = bflo(sh.y) + bflo(sl.y);
    float a3 = bfhi(sh.y) + bfhi(sl.y);
    int i = lo_;
    for (; i + 2 <= hi_; i += 2) {
        int s0 = srclist[i], s1 = srclist[i + 1];
        uint2 h0 = *(const uint2*)(Fhi + (size_t)s0 * HDIM + c);
        uint2 l0 = *(const uint2*)(Flo + (size_t)s0 * HDIM + c);
        uint2 h1 = *(const uint2*)(Fhi + (size_t)s1 * HDIM + c);
        uint2 l1 = *(const uint2*)(Flo + (size_t)s1 * HDIM + c);
        a0 += bflo(h0.x) + bflo(l0.x) + bflo(h1.x) + bflo(l1.x);
        a1 += bfhi(h0.x) + bfhi(l0.x) + bfhi(h1.x) + bfhi(l1.x);
        a2 += bflo(h0.y) + bflo(l0.y) + bflo(h1.y) + bflo(l1.y);
        a3 += bfhi(h0.y) + bfhi(l0.y) + bfhi(h1.y) + bfhi(l1.y);
    }
    for (; i < hi_; ++i) {
        int s = srclist[i];
        uint2 vh = *(const uint2*)(Fhi + (size_t)s * HDIM + c);
        uint2 vl = *(const uint2*)(Flo + (size_t)s * HDIM + c);
        a0 += bflo(vh.x) + bflo(vl.x);
        a1 += bfhi(vh.x) + bfhi(vl.x);
        a2 += bflo(vh.y) + bflo(vl.y);
        a3 += bfhi(vh.y) + bfhi(vl.y);
    }
    ushort h0 = f2bf(a0), h1 = f2bf(a1), h2 = f2bf(a2), h3 = f2bf(a3);
    ushort l0 = f2bf(a0 - bf2f(h0)), l1 = f2bf(a1 - bf2f(h1));
    ushort l2 = f2bf(a2 - bf2f(h2)), l3 = f2bf(a3 - bf2f(h3));
    uint2 oh, ol;
    oh.x = (unsigned)h0 | ((unsigned)h1 << 16); oh.y = (unsigned)h2 | ((unsigned)h3 << 16);
    ol.x = (unsigned)l0 | ((unsigned)l1 << 16); ol.y = (unsigned)l2 | ((unsigned)l3 << 16);
    *(uint2*)(Zhi + sbase) = oh;
    *(uint2*)(Zlo + sbase) = ol;
}

// ---------------------------------------------------------------------------
// split-bf16 MFMA GEMM (unchanged from round 6)
// ---------------------------------------------------------------------------
template<int K, bool SPLIT_OUT>
__global__ __launch_bounds__(256) void mfma_gemm_kernel(
    const ushort* __restrict__ Ahi, const ushort* __restrict__ Alo,
    const ushort* __restrict__ Bthi, const ushort* __restrict__ Btlo,
    const float* __restrict__ Bias, float* __restrict__ OUTf,
    ushort* __restrict__ OUThi, ushort* __restrict__ OUTlo, int Nrows)
{
    __shared__ ushort As[2][64][40];
    __shared__ ushort Ws[2][256][40];
    const int t    = threadIdx.x;
    const int wv   = t >> 6;
    const int lane = t & 63;
    const int l15  = lane & 15;
    const int l4   = lane >> 4;
    const int row0 = blockIdx.x * 64;
    const int wc0  = wv * 64;

    f32x4 acc[4][4];
#pragma unroll
    for (int m = 0; m < 4; ++m)
#pragma unroll
        for (int n = 0; n < 4; ++n) acc[m][n] = (f32x4){0.f, 0.f, 0.f, 0.f};

    const int ar = t >> 2;
    const int as = (t & 3) * 8;
    const int grow = min(row0 + ar, Nrows - 1);
    const size_t abase = (size_t)grow * K + as;

    for (int k0 = 0; k0 < K; k0 += 32) {
        *(uint4*)&As[0][ar][as] = *(const uint4*)(Ahi + abase + k0);
        *(uint4*)&As[1][ar][as] = *(const uint4*)(Alo + abase + k0);
#pragma unroll
        for (int i = 0; i < 4; ++i) {
            int sid = t + i * 256;
            int wc  = sid >> 2;
            int wsg = (sid & 3) * 8;
            size_t wb = (size_t)wc * K + k0 + wsg;
            *(uint4*)&Ws[0][wc][wsg] = *(const uint4*)(Bthi + wb);
            *(uint4*)&Ws[1][wc][wsg] = *(const uint4*)(Btlo + wb);
        }
        __syncthreads();

        bf16x8 ah[4], al[4], bh[4], bl[4];
#pragma unroll
        for (int m = 0; m < 4; ++m) {
            ah[m] = *(const bf16x8*)&As[0][m * 16 + l15][l4 * 8];
            al[m] = *(const bf16x8*)&As[1][m * 16 + l15][l4 * 8];
        }
#pragma unroll
        for (int n = 0; n < 4; ++n) {
            bh[n] = *(const bf16x8*)&Ws[0][wc0 + n * 16 + l15][l4 * 8];
            bl[n] = *(const bf16x8*)&Ws[1][wc0 + n * 16 + l15][l4 * 8];
        }
#pragma unroll
        for (int m = 0; m < 4; ++m)
#pragma unroll
            for (int n = 0; n < 4; ++n) {
                acc[m][n] = __builtin_amdgcn_mfma_f32_16x16x32_bf16(ah[m], bh[n], acc[m][n], 0, 0, 0);
                acc[m][n] = __builtin_amdgcn_mfma_f32_16x16x32_bf16(ah[m], bl[n], acc[m][n], 0, 0, 0);
                acc[m][n] = __builtin_amdgcn_mfma_f32_16x16x32_bf16(al[m], bh[n], acc[m][n], 0, 0, 0);
            }
        __syncthreads();
    }

#pragma unroll
    for (int n = 0; n < 4; ++n) {
        const int ocol = wc0 + n * 16 + l15;
        const float bs = Bias[ocol];
#pragma unroll
        for (int m = 0; m < 4; ++m) {
#pragma unroll
            for (int r = 0; r < 4; ++r) {
                int orow = row0 + m * 16 + l4 * 4 + r;
                if (orow < Nrows) {
                    float v = fmaxf(acc[m][n][r] + bs, 0.f);
                    size_t o = (size_t)orow * HDIM + ocol;
                    if (SPLIT_OUT) {
                        ushort h = f2bf(v);
                        OUThi[o] = h;
                        OUTlo[o] = f2bf(v - bf2f(h));
                    } else {
                        OUTf[o] = v;
                    }
                }
            }
        }
    }
}

// ---------------------------------------------------------------------------
// pooling phase 1: grid = G * PSPLIT blocks. Block (g,s) reduces its node
// chunk -> partial sum/max [G][PSPLIT][256]. Row loop unrolled x4 with
// independent accumulators (keeps 4+ loads in flight per thread).
// ---------------------------------------------------------------------------
__global__ __launch_bounds__(256) void pool_partial_kernel(
    const float* __restrict__ h2, const int* __restrict__ batch,
    float* __restrict__ psum, float* __restrict__ pmax, int N)
{
    const int g = blockIdx.x / PSPLIT;
    const int s = blockIdx.x % PSPLIT;
    const int t = threadIdx.x;

    __shared__ int s_bounds[2];
    if (t < 2) {
        int target = g + t;
        int lo = 0, hi = N;
        while (lo < hi) {
            int mid = (lo + hi) >> 1;
            if (batch[mid] < target) lo = mid + 1; else hi = mid;
        }
        s_bounds[t] = lo;
    }
    __syncthreads();
    const int glo = s_bounds[0], ghi = s_bounds[1];
    const int cnt = ghi - glo;
    const int chunk = (cnt + PSPLIT - 1) / PSPLIT;
    const int clo = glo + s * chunk;
    const int chi = min(clo + chunk, ghi);

    float s0 = 0.f, s1 = 0.f, s2 = 0.f, s3 = 0.f;
    float m0 = -INFINITY, m1 = -INFINITY, m2 = -INFINITY, m3 = -INFINITY;
    int n = clo;
    for (; n + 4 <= chi; n += 4) {
        float v0 = h2[(size_t)(n + 0) * HDIM + t];
        float v1 = h2[(size_t)(n + 1) * HDIM + t];
        float v2 = h2[(size_t)(n + 2) * HDIM + t];
        float v3 = h2[(size_t)(n + 3) * HDIM + t];
        s0 += v0; m0 = fmaxf(m0, v0);
        s1 += v1; m1 = fmaxf(m1, v1);
        s2 += v2; m2 = fmaxf(m2, v2);
        s3 += v3; m3 = fmaxf(m3, v3);
    }
    for (; n < chi; ++n) {
        float v = h2[(size_t)n * HDIM + t];
        s0 += v; m0 = fmaxf(m0, v);
    }
    size_t o = (size_t)blockIdx.x * HDIM + t;
    psum[o] = (s0 + s1) + (s2 + s3);
    pmax[o] = fmaxf(fmaxf(m0, m1), fmaxf(m2, m3));
}

// ---------------------------------------------------------------------------
// pooling phase 2 + final MLP: one block per graph
// ---------------------------------------------------------------------------
__global__ __launch_bounds__(256) void pool_final_kernel(
    const float* __restrict__ psum, const float* __restrict__ pmax,
    const int* __restrict__ batch,
    const float* __restrict__ Wf1, const float* __restrict__ bf1,
    const float* __restrict__ Wf2, const float* __restrict__ bf2,
    float* __restrict__ out, int N)
{
    const int g = blockIdx.x;
    const int t = threadIdx.x;

    __shared__ int s_bounds[2];
    if (t < 2) {
        int target = g + t;
        int lo = 0, hi = N;
        while (lo < hi) {
            int mid = (lo + hi) >> 1;
            if (batch[mid] < target) lo = mid + 1; else hi = mid;
        }
        s_bounds[t] = lo;
    }
    __syncthreads();
    const int cnt = s_bounds[1] - s_bounds[0];

    float sum = 0.f, mx = -INFINITY;
    const size_t gbase = (size_t)g * PSPLIT * HDIM + t;
#pragma unroll
    for (int s = 0; s < PSPLIT; ++s) {
        sum += psum[gbase + (size_t)s * HDIM];
        mx = fmaxf(mx, pmax[gbase + (size_t)s * HDIM]);
    }

    __shared__ float p[2 * HDIM];
    p[t]        = sum / (float)(cnt > 1 ? cnt : 1);
    p[HDIM + t] = (cnt > 0) ? mx : 0.f;
    __syncthreads();

    float acc = bf1[t];
#pragma unroll 8
    for (int k = 0; k < 2 * HDIM; ++k)
        acc += p[k] * Wf1[k * HDIM + t];
    float hval = fmaxf(acc, 0.f);

    float partial = hval * Wf2[t];
#pragma unroll
    for (int off = 32; off > 0; off >>= 1)
        partial += __shfl_down(partial, off);
    __shared__ float red[4];
    if ((t & 63) == 0) red[t >> 6] = partial;
    __syncthreads();
    if (t == 0) out[g] = red[0] + red[1] + red[2] + red[3] + bf2[0];
}

// ---------------------------------------------------------------------------
extern "C" void kernel_launch(void* const* d_in, const int* in_sizes, int n_in,
                              void* d_out, int out_size, void* d_ws, size_t ws_size,
                              hipStream_t stream)
{
    const float* x     = (const float*)d_in[0];
    const int*   ei    = (const int*)d_in[1];
    const int*   batch = (const int*)d_in[2];
    const float* W1 = (const float*)d_in[3];
    const float* b1 = (const float*)d_in[4];
    const float* W2 = (const float*)d_in[5];
    const float* b2 = (const float*)d_in[6];
    const float* W3 = (const float*)d_in[7];
    const float* b3 = (const float*)d_in[8];
    const float* W4 = (const float*)d_in[9];
    const float* b4 = (const float*)d_in[10];
    const float* Wf1 = (const float*)d_in[11];
    const float* bf1 = (const float*)d_in[12];
    const float* Wf2 = (const float*)d_in[13];
    const float* bf2 = (const float*)d_in[14];
    float* out = (float*)d_out;

    const int N  = in_sizes[0] / D_IN;   // 50000
    const int E  = in_sizes[1] / 2;      // 600000
    const int Gn = out_size;             // 128

    // ---- workspace layout ----
    const size_t R = (size_t)N * HDIM;
    float* R0f = (float*)d_ws;
    float* R1f = R0f + R;
    ushort* R0u = (ushort*)R0f;
    ushort* R1u = (ushort*)R1f;

    ushort* wbuf = (ushort*)(R1f + R);
    ushort* W1thi = wbuf;
    ushort* W1tlo = W1thi + 128 * 256;
    ushort* W2thi = W1tlo + 128 * 256;
    ushort* W2tlo = W2thi + 256 * 256;
    ushort* W3thi = W2tlo + 256 * 256;
    ushort* W3tlo = W3thi + 256 * 256;
    ushort* W4thi = W3tlo + 256 * 256;
    ushort* W4tlo = W4thi + 256 * 256;

    int* rowptr  = (int*)(W4tlo + 256 * 256);
    int* cursor  = rowptr + (N + 1);
    int* srclist = cursor + N;
    float* psum  = (float*)(srclist + E);
    float* pmax  = psum + (size_t)Gn * PSPLIT * HDIM;

    const int gblocks = (N + 63) / 64;
    const int eblocks = (E + 255) / 256;
    const int wblocks = (N + 3) / 4;

    // ---- CSR build ----
    zero_int_kernel<<<64, 256, 0, stream>>>(cursor, N);
    hist_kernel<<<eblocks, 256, 0, stream>>>(ei, cursor, E);
    scan_kernel<<<1, 1024, 0, stream>>>(cursor, rowptr, N);
    fill_kernel<<<eblocks, 256, 0, stream>>>(ei, cursor, srclist, E);

    // ---- weight split+transpose ----
    wsplit_kernel<128><<<128, 256, 0, stream>>>(W1, W1thi, W1tlo);
    wsplit_kernel<256><<<256, 256, 0, stream>>>(W2, W2thi, W2tlo);
    wsplit_kernel<256><<<256, 256, 0, stream>>>(W3, W3thi, W3tlo);
    wsplit_kernel<256><<<256, 256, 0, stream>>>(W4, W4thi, W4tlo);

    // bf16 array views within regions
    ushort* Z1hi = R0u;                 ushort* Z1lo = R0u + (size_t)N * D_IN;
    ushort* T1hi = R1u;                 ushort* T1lo = R1u + R;
    ushort* H1hi = R0u;                 ushort* H1lo = R0u + R;
    ushort* Z2hi = R1u;                 ushort* Z2lo = R1u + R;
    ushort* T2hi = R0u;                 ushort* T2lo = R0u + R;
    float*  H2   = R1f;

    // ---- conv1 ----
    gather1_kernel<<<wblocks, 256, 0, stream>>>(x, rowptr, srclist, Z1hi, Z1lo, N);
    mfma_gemm_kernel<128, true><<<gblocks, 256, 0, stream>>>(
        Z1hi, Z1lo, W1thi, W1tlo, b1, nullptr, T1hi, T1lo, N);
    mfma_gemm_kernel<256, true><<<gblocks, 256, 0, stream>>>(
        T1hi, T1lo, W2thi, W2tlo, b2, nullptr, H1hi, H1lo, N);

    // ---- conv2 ----
    gather2_kernel<<<wblocks, 256, 0, stream>>>(H1hi, H1lo, rowptr, srclist, Z2hi, Z2lo, N);
    mfma_gemm_kernel<256, true><<<gblocks, 256, 0, stream>>>(
        Z2hi, Z2lo, W3thi, W3tlo, b3, nullptr, T2hi, T2lo, N);
    mfma_gemm_kernel<256, false><<<gblocks, 256, 0, stream>>>(
        T2hi, T2lo, W4thi, W4tlo, b4, H2, nullptr, nullptr, N);

    // ---- pooling (2-phase) + final MLP ----
    pool_partial_kernel<<<Gn * PSPLIT, 256, 0, stream>>>(H2, batch, psum, pmax, N);
    pool_final_kernel<<<Gn, 256, 0, stream>>>(psum, pmax, batch,
                                              Wf1, bf1, Wf2, bf2, out, N);
}

// Round 8
// 540.526 us; speedup vs baseline: 8.9458x; 1.1823x over previous
//
#include <hip/hip_runtime.h>
#include <math.h>

#define D_IN 128
#define HDIM 256
#define PSPLIT 8

typedef __attribute__((ext_vector_type(8))) short bf16x8;
typedef __attribute__((ext_vector_type(4))) float f32x4;

// ---------------- bf16 helpers (RNE) ----------------
__device__ inline ushort f2bf(float v) {
    union { float f; unsigned u; } c; c.f = v;
    unsigned u = c.u;
    return (ushort)((u + 0x7FFFu + ((u >> 16) & 1u)) >> 16);
}
__device__ inline float bf2f(ushort h) {
    union { unsigned u; float f; } c; c.u = ((unsigned)h) << 16; return c.f;
}
__device__ inline float bflo(unsigned u) {
    union { unsigned u; float f; } c; c.u = u << 16; return c.f;
}
__device__ inline float bfhi(unsigned u) {
    union { unsigned u; float f; } c; c.u = u & 0xFFFF0000u; return c.f;
}

// ---------------------------------------------------------------------------
__global__ __launch_bounds__(256) void zero_int_kernel(int* __restrict__ p, int n) {
    int i = blockIdx.x * 256 + threadIdx.x;
    int stride = gridDim.x * 256;
    for (; i < n; i += stride) p[i] = 0;
}

// ---------------------------------------------------------------------------
// CSR build: histogram -> 3-phase scan -> fill
// ---------------------------------------------------------------------------
__global__ __launch_bounds__(256) void hist_kernel(
    const int* __restrict__ ei, int* __restrict__ deg, int E)
{
    int e = blockIdx.x * 256 + threadIdx.x;
    if (e < E) atomicAdd(&deg[ei[E + e]], 1);
}

// phase A: per-256-chunk LDS scan; rowptr[i] = local exclusive prefix
__global__ __launch_bounds__(256) void scan_local_kernel(
    const int* __restrict__ deg, int* __restrict__ rowptr,
    int* __restrict__ bsum, int N)
{
    __shared__ int sh[256];
    const int t = threadIdx.x;
    const int i = blockIdx.x * 256 + t;
    int v = (i < N) ? deg[i] : 0;
    sh[t] = v;
    __syncthreads();
#pragma unroll
    for (int off = 1; off < 256; off <<= 1) {
        int x = (t >= off) ? sh[t - off] : 0;
        __syncthreads();
        sh[t] += x;
        __syncthreads();
    }
    if (i < N) rowptr[i] = sh[t] - v;          // exclusive within chunk
    if (t == 255) bsum[blockIdx.x] = sh[255];  // chunk total
}

// phase B: single block scans the (<=256) block sums; writes rowptr[N]=E
__global__ __launch_bounds__(256) void scan_bsum_kernel(
    int* __restrict__ bsum, int* __restrict__ rowptr, int nb, int N)
{
    __shared__ int sh[256];
    const int t = threadIdx.x;
    int v = (t < nb) ? bsum[t] : 0;
    sh[t] = v;
    __syncthreads();
#pragma unroll
    for (int off = 1; off < 256; off <<= 1) {
        int x = (t >= off) ? sh[t - off] : 0;
        __syncthreads();
        sh[t] += x;
        __syncthreads();
    }
    if (t < nb) bsum[t] = sh[t] - v;           // exclusive block offsets
    if (t == 255) rowptr[N] = sh[255];         // total == E
}

// phase C: add block offset; materialize rowptr and cursor
__global__ __launch_bounds__(256) void scan_apply_kernel(
    int* __restrict__ rowptr, int* __restrict__ cursor,
    const int* __restrict__ bsum, int N)
{
    int i = blockIdx.x * 256 + threadIdx.x;
    if (i < N) {
        int v = rowptr[i] + bsum[blockIdx.x];
        rowptr[i] = v;
        cursor[i] = v;
    }
}

__global__ __launch_bounds__(256) void fill_kernel(
    const int* __restrict__ ei, int* __restrict__ cursor,
    int* __restrict__ srclist, int E)
{
    int e = blockIdx.x * 256 + threadIdx.x;
    if (e < E) {
        int s = ei[e];
        int d = ei[E + e];
        int pos = atomicAdd(&cursor[d], 1);
        srclist[pos] = s;
    }
}

// ---------------------------------------------------------------------------
// weight split + transpose:  W[K][256] fp32  ->  Wt_hi/Wt_lo [256][K] bf16
// ---------------------------------------------------------------------------
template<int K>
__global__ __launch_bounds__(256) void wsplit_kernel(
    const float* __restrict__ W, ushort* __restrict__ Wthi, ushort* __restrict__ Wtlo)
{
    int idx = blockIdx.x * 256 + threadIdx.x;
    if (idx >= K * 256) return;
    int k = idx >> 8;
    int c = idx & 255;
    float v = W[idx];
    ushort h = f2bf(v);
    Wthi[c * K + k] = h;
    Wtlo[c * K + k] = f2bf(v - bf2f(h));
}

// ---------------------------------------------------------------------------
// gather1: z1[v] = x[v] + sum x[u]   (fp32 in, split-bf16 out)  D=128
// ---------------------------------------------------------------------------
__global__ __launch_bounds__(256) void gather1_kernel(
    const float* __restrict__ feat, const int* __restrict__ rowptr,
    const int* __restrict__ srclist, ushort* __restrict__ Zhi,
    ushort* __restrict__ Zlo, int N)
{
    const int wave = (blockIdx.x * 256 + threadIdx.x) >> 6;
    const int lane = threadIdx.x & 63;
    if (wave >= N) return;
    const int lo_ = rowptr[wave], hi_ = rowptr[wave + 1];
    const int c = lane * 2;
    float2 acc = *(const float2*)(feat + (size_t)wave * D_IN + c);
    int i = lo_;
    for (; i + 4 <= hi_; i += 4) {
        int s0 = srclist[i + 0], s1 = srclist[i + 1];
        int s2 = srclist[i + 2], s3 = srclist[i + 3];
        float2 v0 = *(const float2*)(feat + (size_t)s0 * D_IN + c);
        float2 v1 = *(const float2*)(feat + (size_t)s1 * D_IN + c);
        float2 v2 = *(const float2*)(feat + (size_t)s2 * D_IN + c);
        float2 v3 = *(const float2*)(feat + (size_t)s3 * D_IN + c);
        acc.x += v0.x + v1.x + v2.x + v3.x;
        acc.y += v0.y + v1.y + v2.y + v3.y;
    }
    for (; i < hi_; ++i) {
        int s = srclist[i];
        float2 v = *(const float2*)(feat + (size_t)s * D_IN + c);
        acc.x += v.x; acc.y += v.y;
    }
    ushort h0 = f2bf(acc.x), h1 = f2bf(acc.y);
    ushort l0 = f2bf(acc.x - bf2f(h0)), l1 = f2bf(acc.y - bf2f(h1));
    size_t o = ((size_t)wave * D_IN + c) >> 1;
    ((unsigned*)Zhi)[o] = (unsigned)h0 | ((unsigned)h1 << 16);
    ((unsigned*)Zlo)[o] = (unsigned)l0 | ((unsigned)l1 << 16);
}

// ---------------------------------------------------------------------------
// gather2: z2[v] = h1[v] + sum h1[u]  (split-bf16 in & out)  D=256
// ---------------------------------------------------------------------------
__global__ __launch_bounds__(256) void gather2_kernel(
    const ushort* __restrict__ Fhi, const ushort* __restrict__ Flo,
    const int* __restrict__ rowptr, const int* __restrict__ srclist,
    ushort* __restrict__ Zhi, ushort* __restrict__ Zlo, int N)
{
    const int wave = (blockIdx.x * 256 + threadIdx.x) >> 6;
    const int lane = threadIdx.x & 63;
    if (wave >= N) return;
    const int lo_ = rowptr[wave], hi_ = rowptr[wave + 1];
    const int c = lane * 4;
    const size_t sbase = (size_t)wave * HDIM + c;
    uint2 sh = *(const uint2*)(Fhi + sbase);
    uint2 sl = *(const uint2*)(Flo + sbase);
    float a0 = bflo(sh.x) + bflo(sl.x);
    float a1 = bfhi(sh.x) + bfhi(sl.x);
    float a2 = bflo(sh.y) + bflo(sl.y);
    float a3 = bfhi(sh.y) + bfhi(sl.y);
    int i = lo_;
    for (; i + 2 <= hi_; i += 2) {
        int s0 = srclist[i], s1 = srclist[i + 1];
        uint2 h0 = *(const uint2*)(Fhi + (size_t)s0 * HDIM + c);
        uint2 l0 = *(const uint2*)(Flo + (size_t)s0 * HDIM + c);
        uint2 h1 = *(const uint2*)(Fhi + (size_t)s1 * HDIM + c);
        uint2 l1 = *(const uint2*)(Flo + (size_t)s1 * HDIM + c);
        a0 += bflo(h0.x) + bflo(l0.x) + bflo(h1.x) + bflo(l1.x);
        a1 += bfhi(h0.x) + bfhi(l0.x) + bfhi(h1.x) + bfhi(l1.x);
        a2 += bflo(h0.y) + bflo(l0.y) + bflo(h1.y) + bflo(l1.y);
        a3 += bfhi(h0.y) + bfhi(l0.y) + bfhi(h1.y) + bfhi(l1.y);
    }
    for (; i < hi_; ++i) {
        int s = srclist[i];
        uint2 vh = *(const uint2*)(Fhi + (size_t)s * HDIM + c);
        uint2 vl = *(const uint2*)(Flo + (size_t)s * HDIM + c);
        a0 += bflo(vh.x) + bflo(vl.x);
        a1 += bfhi(vh.x) + bfhi(vl.x);
        a2 += bflo(vh.y) + bflo(vl.y);
        a3 += bfhi(vh.y) + bfhi(vl.y);
    }
    ushort h0 = f2bf(a0), h1 = f2bf(a1), h2 = f2bf(a2), h3 = f2bf(a3);
    ushort l0 = f2bf(a0 - bf2f(h0)), l1 = f2bf(a1 - bf2f(h1));
    ushort l2 = f2bf(a2 - bf2f(h2)), l3 = f2bf(a3 - bf2f(h3));
    uint2 oh, ol;
    oh.x = (unsigned)h0 | ((unsigned)h1 << 16); oh.y = (unsigned)h2 | ((unsigned)h3 << 16);
    ol.x = (unsigned)l0 | ((unsigned)l1 << 16); ol.y = (unsigned)l2 | ((unsigned)l3 << 16);
    *(uint2*)(Zhi + sbase) = oh;
    *(uint2*)(Zlo + sbase) = ol;
}

// ---------------------------------------------------------------------------
// split-bf16 MFMA GEMM (unchanged)
// ---------------------------------------------------------------------------
template<int K, bool SPLIT_OUT>
__global__ __launch_bounds__(256) void mfma_gemm_kernel(
    const ushort* __restrict__ Ahi, const ushort* __restrict__ Alo,
    const ushort* __restrict__ Bthi, const ushort* __restrict__ Btlo,
    const float* __restrict__ Bias, float* __restrict__ OUTf,
    ushort* __restrict__ OUThi, ushort* __restrict__ OUTlo, int Nrows)
{
    __shared__ ushort As[2][64][40];
    __shared__ ushort Ws[2][256][40];
    const int t    = threadIdx.x;
    const int wv   = t >> 6;
    const int lane = t & 63;
    const int l15  = lane & 15;
    const int l4   = lane >> 4;
    const int row0 = blockIdx.x * 64;
    const int wc0  = wv * 64;

    f32x4 acc[4][4];
#pragma unroll
    for (int m = 0; m < 4; ++m)
#pragma unroll
        for (int n = 0; n < 4; ++n) acc[m][n] = (f32x4){0.f, 0.f, 0.f, 0.f};

    const int ar = t >> 2;
    const int as = (t & 3) * 8;
    const int grow = min(row0 + ar, Nrows - 1);
    const size_t abase = (size_t)grow * K + as;

    for (int k0 = 0; k0 < K; k0 += 32) {
        *(uint4*)&As[0][ar][as] = *(const uint4*)(Ahi + abase + k0);
        *(uint4*)&As[1][ar][as] = *(const uint4*)(Alo + abase + k0);
#pragma unroll
        for (int i = 0; i < 4; ++i) {
            int sid = t + i * 256;
            int wc  = sid >> 2;
            int wsg = (sid & 3) * 8;
            size_t wb = (size_t)wc * K + k0 + wsg;
            *(uint4*)&Ws[0][wc][wsg] = *(const uint4*)(Bthi + wb);
            *(uint4*)&Ws[1][wc][wsg] = *(const uint4*)(Btlo + wb);
        }
        __syncthreads();

        bf16x8 ah[4], al[4], bh[4], bl[4];
#pragma unroll
        for (int m = 0; m < 4; ++m) {
            ah[m] = *(const bf16x8*)&As[0][m * 16 + l15][l4 * 8];
            al[m] = *(const bf16x8*)&As[1][m * 16 + l15][l4 * 8];
        }
#pragma unroll
        for (int n = 0; n < 4; ++n) {
            bh[n] = *(const bf16x8*)&Ws[0][wc0 + n * 16 + l15][l4 * 8];
            bl[n] = *(const bf16x8*)&Ws[1][wc0 + n * 16 + l15][l4 * 8];
        }
#pragma unroll
        for (int m = 0; m < 4; ++m)
#pragma unroll
            for (int n = 0; n < 4; ++n) {
                acc[m][n] = __builtin_amdgcn_mfma_f32_16x16x32_bf16(ah[m], bh[n], acc[m][n], 0, 0, 0);
                acc[m][n] = __builtin_amdgcn_mfma_f32_16x16x32_bf16(ah[m], bl[n], acc[m][n], 0, 0, 0);
                acc[m][n] = __builtin_amdgcn_mfma_f32_16x16x32_bf16(al[m], bh[n], acc[m][n], 0, 0, 0);
            }
        __syncthreads();
    }

#pragma unroll
    for (int n = 0; n < 4; ++n) {
        const int ocol = wc0 + n * 16 + l15;
        const float bs = Bias[ocol];
#pragma unroll
        for (int m = 0; m < 4; ++m) {
#pragma unroll
            for (int r = 0; r < 4; ++r) {
                int orow = row0 + m * 16 + l4 * 4 + r;
                if (orow < Nrows) {
                    float v = fmaxf(acc[m][n][r] + bs, 0.f);
                    size_t o = (size_t)orow * HDIM + ocol;
                    if (SPLIT_OUT) {
                        ushort h = f2bf(v);
                        OUThi[o] = h;
                        OUTlo[o] = f2bf(v - bf2f(h));
                    } else {
                        OUTf[o] = v;
                    }
                }
            }
        }
    }
}

// ---------------------------------------------------------------------------
// pooling phase 1 (unchanged from round 7)
// ---------------------------------------------------------------------------
__global__ __launch_bounds__(256) void pool_partial_kernel(
    const float* __restrict__ h2, const int* __restrict__ batch,
    float* __restrict__ psum, float* __restrict__ pmax, int N)
{
    const int g = blockIdx.x / PSPLIT;
    const int s = blockIdx.x % PSPLIT;
    const int t = threadIdx.x;

    __shared__ int s_bounds[2];
    if (t < 2) {
        int target = g + t;
        int lo = 0, hi = N;
        while (lo < hi) {
            int mid = (lo + hi) >> 1;
            if (batch[mid] < target) lo = mid + 1; else hi = mid;
        }
        s_bounds[t] = lo;
    }
    __syncthreads();
    const int glo = s_bounds[0], ghi = s_bounds[1];
    const int cnt = ghi - glo;
    const int chunk = (cnt + PSPLIT - 1) / PSPLIT;
    const int clo = glo + s * chunk;
    const int chi = min(clo + chunk, ghi);

    float s0 = 0.f, s1 = 0.f, s2 = 0.f, s3 = 0.f;
    float m0 = -INFINITY, m1 = -INFINITY, m2 = -INFINITY, m3 = -INFINITY;
    int n = clo;
    for (; n + 4 <= chi; n += 4) {
        float v0 = h2[(size_t)(n + 0) * HDIM + t];
        float v1 = h2[(size_t)(n + 1) * HDIM + t];
        float v2 = h2[(size_t)(n + 2) * HDIM + t];
        float v3 = h2[(size_t)(n + 3) * HDIM + t];
        s0 += v0; m0 = fmaxf(m0, v0);
        s1 += v1; m1 = fmaxf(m1, v1);
        s2 += v2; m2 = fmaxf(m2, v2);
        s3 += v3; m3 = fmaxf(m3, v3);
    }
    for (; n < chi; ++n) {
        float v = h2[(size_t)n * HDIM + t];
        s0 += v; m0 = fmaxf(m0, v);
    }
    size_t o = (size_t)blockIdx.x * HDIM + t;
    psum[o] = (s0 + s1) + (s2 + s3);
    pmax[o] = fmaxf(fmaxf(m0, m1), fmaxf(m2, m3));
}

// ---------------------------------------------------------------------------
// pooling phase 2 + final MLP (unchanged)
// ---------------------------------------------------------------------------
__global__ __launch_bounds__(256) void pool_final_kernel(
    const float* __restrict__ psum, const float* __restrict__ pmax,
    const int* __restrict__ batch,
    const float* __restrict__ Wf1, const float* __restrict__ bf1,
    const float* __restrict__ Wf2, const float* __restrict__ bf2,
    float* __restrict__ out, int N)
{
    const int g = blockIdx.x;
    const int t = threadIdx.x;

    __shared__ int s_bounds[2];
    if (t < 2) {
        int target = g + t;
        int lo = 0, hi = N;
        while (lo < hi) {
            int mid = (lo + hi) >> 1;
            if (batch[mid] < target) lo = mid + 1; else hi = mid;
        }
        s_bounds[t] = lo;
    }
    __syncthreads();
    const int cnt = s_bounds[1] - s_bounds[0];

    float sum = 0.f, mx = -INFINITY;
    const size_t gbase = (size_t)g * PSPLIT * HDIM + t;
#pragma unroll
    for (int s = 0; s < PSPLIT; ++s) {
        sum += psum[gbase + (size_t)s * HDIM];
        mx = fmaxf(mx, pmax[gbase + (size_t)s * HDIM]);
    }

    __shared__ float p[2 * HDIM];
    p[t]        = sum / (float)(cnt > 1 ? cnt : 1);
    p[HDIM + t] = (cnt > 0) ? mx : 0.f;
    __syncthreads();

    float acc = bf1[t];
#pragma unroll 8
    for (int k = 0; k < 2 * HDIM; ++k)
        acc += p[k] * Wf1[k * HDIM + t];
    float hval = fmaxf(acc, 0.f);

    float partial = hval * Wf2[t];
#pragma unroll
    for (int off = 32; off > 0; off >>= 1)
        partial += __shfl_down(partial, off);
    __shared__ float red[4];
    if ((t & 63) == 0) red[t >> 6] = partial;
    __syncthreads();
    if (t == 0) out[g] = red[0] + red[1] + red[2] + red[3] + bf2[0];
}

// ---------------------------------------------------------------------------
extern "C" void kernel_launch(void* const* d_in, const int* in_sizes, int n_in,
                              void* d_out, int out_size, void* d_ws, size_t ws_size,
                              hipStream_t stream)
{
    const float* x     = (const float*)d_in[0];
    const int*   ei    = (const int*)d_in[1];
    const int*   batch = (const int*)d_in[2];
    const float* W1 = (const float*)d_in[3];
    const float* b1 = (const float*)d_in[4];
    const float* W2 = (const float*)d_in[5];
    const float* b2 = (const float*)d_in[6];
    const float* W3 = (const float*)d_in[7];
    const float* b3 = (const float*)d_in[8];
    const float* W4 = (const float*)d_in[9];
    const float* b4 = (const float*)d_in[10];
    const float* Wf1 = (const float*)d_in[11];
    const float* bf1 = (const float*)d_in[12];
    const float* Wf2 = (const float*)d_in[13];
    const float* bf2 = (const float*)d_in[14];
    float* out = (float*)d_out;

    const int N  = in_sizes[0] / D_IN;   // 50000
    const int E  = in_sizes[1] / 2;      // 600000
    const int Gn = out_size;             // 128

    // ---- workspace layout ----
    const size_t R = (size_t)N * HDIM;
    float* R0f = (float*)d_ws;
    float* R1f = R0f + R;
    ushort* R0u = (ushort*)R0f;
    ushort* R1u = (ushort*)R1f;

    ushort* wbuf = (ushort*)(R1f + R);
    ushort* W1thi = wbuf;
    ushort* W1tlo = W1thi + 128 * 256;
    ushort* W2thi = W1tlo + 128 * 256;
    ushort* W2tlo = W2thi + 256 * 256;
    ushort* W3thi = W2tlo + 256 * 256;
    ushort* W3tlo = W3thi + 256 * 256;
    ushort* W4thi = W3tlo + 256 * 256;
    ushort* W4tlo = W4thi + 256 * 256;

    int* rowptr  = (int*)(W4tlo + 256 * 256);
    int* cursor  = rowptr + (N + 1);
    int* srclist = cursor + N;
    float* psum  = (float*)(srclist + E);
    float* pmax  = psum + (size_t)Gn * PSPLIT * HDIM;
    int* bsum    = (int*)(pmax + (size_t)Gn * PSPLIT * HDIM);

    const int gblocks = (N + 63) / 64;
    const int eblocks = (E + 255) / 256;
    const int wblocks = (N + 3) / 4;
    const int nb      = (N + 255) / 256;   // scan chunks (196)

    // ---- CSR build (multi-block scan) ----
    zero_int_kernel<<<64, 256, 0, stream>>>(cursor, N);
    hist_kernel<<<eblocks, 256, 0, stream>>>(ei, cursor, E);
    scan_local_kernel<<<nb, 256, 0, stream>>>(cursor, rowptr, bsum, N);
    scan_bsum_kernel<<<1, 256, 0, stream>>>(bsum, rowptr, nb, N);
    scan_apply_kernel<<<nb, 256, 0, stream>>>(rowptr, cursor, bsum, N);
    fill_kernel<<<eblocks, 256, 0, stream>>>(ei, cursor, srclist, E);

    // ---- weight split+transpose ----
    wsplit_kernel<128><<<128, 256, 0, stream>>>(W1, W1thi, W1tlo);
    wsplit_kernel<256><<<256, 256, 0, stream>>>(W2, W2thi, W2tlo);
    wsplit_kernel<256><<<256, 256, 0, stream>>>(W3, W3thi, W3tlo);
    wsplit_kernel<256><<<256, 256, 0, stream>>>(W4, W4thi, W4tlo);

    // bf16 array views within regions
    ushort* Z1hi = R0u;                 ushort* Z1lo = R0u + (size_t)N * D_IN;
    ushort* T1hi = R1u;                 ushort* T1lo = R1u + R;
    ushort* H1hi = R0u;                 ushort* H1lo = R0u + R;
    ushort* Z2hi = R1u;                 ushort* Z2lo = R1u + R;
    ushort* T2hi = R0u;                 ushort* T2lo = R0u + R;
    float*  H2   = R1f;

    // ---- conv1 ----
    gather1_kernel<<<wblocks, 256, 0, stream>>>(x, rowptr, srclist, Z1hi, Z1lo, N);
    mfma_gemm_kernel<128, true><<<gblocks, 256, 0, stream>>>(
        Z1hi, Z1lo, W1thi, W1tlo, b1, nullptr, T1hi, T1lo, N);
    mfma_gemm_kernel<256, true><<<gblocks, 256, 0, stream>>>(
        T1hi, T1lo, W2thi, W2tlo, b2, nullptr, H1hi, H1lo, N);

    // ---- conv2 ----
    gather2_kernel<<<wblocks, 256, 0, stream>>>(H1hi, H1lo, rowptr, srclist, Z2hi, Z2lo, N);
    mfma_gemm_kernel<256, true><<<gblocks, 256, 0, stream>>>(
        Z2hi, Z2lo, W3thi, W3tlo, b3, nullptr, T2hi, T2lo, N);
    mfma_gemm_kernel<256, false><<<gblocks, 256, 0, stream>>>(
        T2hi, T2lo, W4thi, W4tlo, b4, H2, nullptr, nullptr, N);

    // ---- pooling (2-phase) + final MLP ----
    pool_partial_kernel<<<Gn * PSPLIT, 256, 0, stream>>>(H2, batch, psum, pmax, N);
    pool_final_kernel<<<Gn, 256, 0, stream>>>(psum, pmax, batch,
                                              Wf1, bf1, Wf2, bf2, out, N);
}

// Round 10
// 523.316 us; speedup vs baseline: 9.2400x; 1.0329x over previous
//
#include <hip/hip_runtime.h>
#include <math.h>

#define D_IN 128
#define HDIM 256
#define PSPLIT 8

typedef __attribute__((ext_vector_type(8))) short bf16x8;
typedef __attribute__((ext_vector_type(4))) float f32x4;

#define GLOBAL_AS __attribute__((address_space(1)))
#define LDS_AS    __attribute__((address_space(3)))

// async 16B/lane global->LDS (dest = wave-uniform base + lane*16)
__device__ __forceinline__ void gload16(const void* g, void* l) {
    __builtin_amdgcn_global_load_lds((const GLOBAL_AS void*)g, (LDS_AS void*)l, 16, 0, 0);
}

// ---------------- bf16 helpers (RNE) ----------------
__device__ inline ushort f2bf(float v) {
    union { float f; unsigned u; } c; c.f = v;
    unsigned u = c.u;
    return (ushort)((u + 0x7FFFu + ((u >> 16) & 1u)) >> 16);
}
__device__ inline float bf2f(ushort h) {
    union { unsigned u; float f; } c; c.u = ((unsigned)h) << 16; return c.f;
}

// ---------------------------------------------------------------------------
__global__ __launch_bounds__(256) void zero_int_kernel(int* __restrict__ p, int n) {
    int i = blockIdx.x * 256 + threadIdx.x;
    int stride = gridDim.x * 256;
    for (; i < n; i += stride) p[i] = 0;
}

// ---------------------------------------------------------------------------
// CSR build: histogram -> 3-phase scan -> fill
// ---------------------------------------------------------------------------
__global__ __launch_bounds__(256) void hist_kernel(
    const int* __restrict__ ei, int* __restrict__ deg, int E)
{
    int e = blockIdx.x * 256 + threadIdx.x;
    if (e < E) atomicAdd(&deg[ei[E + e]], 1);
}

__global__ __launch_bounds__(256) void scan_local_kernel(
    const int* __restrict__ deg, int* __restrict__ rowptr,
    int* __restrict__ bsum, int N)
{
    __shared__ int sh[256];
    const int t = threadIdx.x;
    const int i = blockIdx.x * 256 + t;
    int v = (i < N) ? deg[i] : 0;
    sh[t] = v;
    __syncthreads();
#pragma unroll
    for (int off = 1; off < 256; off <<= 1) {
        int x = (t >= off) ? sh[t - off] : 0;
        __syncthreads();
        sh[t] += x;
        __syncthreads();
    }
    if (i < N) rowptr[i] = sh[t] - v;
    if (t == 255) bsum[blockIdx.x] = sh[255];
}

__global__ __launch_bounds__(256) void scan_bsum_kernel(
    int* __restrict__ bsum, int* __restrict__ rowptr, int nb, int N)
{
    __shared__ int sh[256];
    const int t = threadIdx.x;
    int v = (t < nb) ? bsum[t] : 0;
    sh[t] = v;
    __syncthreads();
#pragma unroll
    for (int off = 1; off < 256; off <<= 1) {
        int x = (t >= off) ? sh[t - off] : 0;
        __syncthreads();
        sh[t] += x;
        __syncthreads();
    }
    if (t < nb) bsum[t] = sh[t] - v;
    if (t == 255) rowptr[N] = sh[255];
}

__global__ __launch_bounds__(256) void scan_apply_kernel(
    int* __restrict__ rowptr, int* __restrict__ cursor,
    const int* __restrict__ bsum, int N)
{
    int i = blockIdx.x * 256 + threadIdx.x;
    if (i < N) {
        int v = rowptr[i] + bsum[blockIdx.x];
        rowptr[i] = v;
        cursor[i] = v;
    }
}

__global__ __launch_bounds__(256) void fill_kernel(
    const int* __restrict__ ei, int* __restrict__ cursor,
    int* __restrict__ srclist, int E)
{
    int e = blockIdx.x * 256 + threadIdx.x;
    if (e < E) {
        int s = ei[e];
        int d = ei[E + e];
        int pos = atomicAdd(&cursor[d], 1);
        srclist[pos] = s;
    }
}

// ---------------------------------------------------------------------------
// weight split + transpose:  W[K][256] fp32  ->  Wt_hi/Wt_lo [256][K] bf16
// ---------------------------------------------------------------------------
template<int K>
__global__ __launch_bounds__(256) void wsplit_kernel(
    const float* __restrict__ W, ushort* __restrict__ Wthi, ushort* __restrict__ Wtlo)
{
    int idx = blockIdx.x * 256 + threadIdx.x;
    if (idx >= K * 256) return;
    int k = idx >> 8;
    int c = idx & 255;
    float v = W[idx];
    ushort h = f2bf(v);
    Wthi[c * K + k] = h;
    Wtlo[c * K + k] = f2bf(v - bf2f(h));
}

// ---------------------------------------------------------------------------
// gather1: z1[v] = x[v] + sum x[u]   (fp32 in, split-bf16 out)  D=128
// TWO nodes per wave: 32 lanes x float4 each (16B loads)
// ---------------------------------------------------------------------------
__global__ __launch_bounds__(256) void gather1_kernel(
    const float* __restrict__ feat, const int* __restrict__ rowptr,
    const int* __restrict__ srclist, ushort* __restrict__ Zhi,
    ushort* __restrict__ Zlo, int N)
{
    const int wid  = (blockIdx.x * 256 + threadIdx.x) >> 6;
    const int lane = threadIdx.x & 63;
    const int node = wid * 2 + (lane >> 5);
    if (node >= N) return;
    const int lo_ = rowptr[node], hi_ = rowptr[node + 1];
    const int c = (lane & 31) * 4;
    float4 a = *(const float4*)(feat + (size_t)node * D_IN + c);
    float s0 = a.x, s1 = a.y, s2 = a.z, s3 = a.w;
    int i = lo_;
    for (; i + 4 <= hi_; i += 4) {
        int n0 = srclist[i], n1 = srclist[i + 1], n2 = srclist[i + 2], n3 = srclist[i + 3];
        float4 v0 = *(const float4*)(feat + (size_t)n0 * D_IN + c);
        float4 v1 = *(const float4*)(feat + (size_t)n1 * D_IN + c);
        float4 v2 = *(const float4*)(feat + (size_t)n2 * D_IN + c);
        float4 v3 = *(const float4*)(feat + (size_t)n3 * D_IN + c);
        s0 += v0.x + v1.x + v2.x + v3.x;
        s1 += v0.y + v1.y + v2.y + v3.y;
        s2 += v0.z + v1.z + v2.z + v3.z;
        s3 += v0.w + v1.w + v2.w + v3.w;
    }
    for (; i < hi_; ++i) {
        int s = srclist[i];
        float4 v = *(const float4*)(feat + (size_t)s * D_IN + c);
        s0 += v.x; s1 += v.y; s2 += v.z; s3 += v.w;
    }
    ushort h0 = f2bf(s0), h1 = f2bf(s1), h2 = f2bf(s2), h3 = f2bf(s3);
    ushort l0 = f2bf(s0 - bf2f(h0)), l1 = f2bf(s1 - bf2f(h1));
    ushort l2 = f2bf(s2 - bf2f(h2)), l3 = f2bf(s3 - bf2f(h3));
    size_t o = (size_t)node * D_IN + c;
    uint2 oh, ol;
    oh.x = (unsigned)h0 | ((unsigned)h1 << 16); oh.y = (unsigned)h2 | ((unsigned)h3 << 16);
    ol.x = (unsigned)l0 | ((unsigned)l1 << 16); ol.y = (unsigned)l2 | ((unsigned)l3 << 16);
    *(uint2*)(Zhi + o) = oh;
    *(uint2*)(Zlo + o) = ol;
}

// ---------------------------------------------------------------------------
// gather2: z2[v] = h1[v] + sum h1[u]  (fp32 in, split-bf16 out)  D=256
// one wave per node, float4/lane, neighbor loop unrolled x4
// ---------------------------------------------------------------------------
__global__ __launch_bounds__(256) void gather2_kernel(
    const float* __restrict__ F, const int* __restrict__ rowptr,
    const int* __restrict__ srclist,
    ushort* __restrict__ Zhi, ushort* __restrict__ Zlo, int N)
{
    const int node = (blockIdx.x * 256 + threadIdx.x) >> 6;
    const int lane = threadIdx.x & 63;
    if (node >= N) return;
    const int lo_ = rowptr[node], hi_ = rowptr[node + 1];
    const int c = lane * 4;
    float4 a = *(const float4*)(F + (size_t)node * HDIM + c);
    float s0 = a.x, s1 = a.y, s2 = a.z, s3 = a.w;
    int i = lo_;
    for (; i + 4 <= hi_; i += 4) {
        int n0 = srclist[i], n1 = srclist[i + 1], n2 = srclist[i + 2], n3 = srclist[i + 3];
        float4 v0 = *(const float4*)(F + (size_t)n0 * HDIM + c);
        float4 v1 = *(const float4*)(F + (size_t)n1 * HDIM + c);
        float4 v2 = *(const float4*)(F + (size_t)n2 * HDIM + c);
        float4 v3 = *(const float4*)(F + (size_t)n3 * HDIM + c);
        s0 += v0.x + v1.x + v2.x + v3.x;
        s1 += v0.y + v1.y + v2.y + v3.y;
        s2 += v0.z + v1.z + v2.z + v3.z;
        s3 += v0.w + v1.w + v2.w + v3.w;
    }
    for (; i < hi_; ++i) {
        int s = srclist[i];
        float4 v = *(const float4*)(F + (size_t)s * HDIM + c);
        s0 += v.x; s1 += v.y; s2 += v.z; s3 += v.w;
    }
    ushort h0 = f2bf(s0), h1 = f2bf(s1), h2 = f2bf(s2), h3 = f2bf(s3);
    ushort l0 = f2bf(s0 - bf2f(h0)), l1 = f2bf(s1 - bf2f(h1));
    ushort l2 = f2bf(s2 - bf2f(h2)), l3 = f2bf(s3 - bf2f(h3));
    size_t o = (size_t)node * HDIM + c;
    uint2 oh, ol;
    oh.x = (unsigned)h0 | ((unsigned)h1 << 16); oh.y = (unsigned)h2 | ((unsigned)h3 << 16);
    ol.x = (unsigned)l0 | ((unsigned)l1 << 16); ol.y = (unsigned)l2 | ((unsigned)l3 << 16);
    *(uint2*)(Zhi + o) = oh;
    *(uint2*)(Zlo + o) = ol;
}

// ---------------------------------------------------------------------------
// split-bf16 MFMA GEMM with global_load_lds staging.
// LDS linear [rows][32] ushorts (64B rows). XOR chunk swizzle (involution):
//   staged slot c of row r holds global k-chunk  c ^ ((r>>1)&3)
//   (lane l stages slot l&3, fetching chunk (l&3)^((l>>3)&3))
//   ds_read of global chunk l4 from row base+l15 uses slot l4^((l15>>1)&3)
// -> 16 same-l4 lanes spread over 8 bank regions (2-way, free).
// ---------------------------------------------------------------------------
template<int K, bool SPLIT_OUT>
__global__ __launch_bounds__(256) void mfma_gemm_kernel(
    const ushort* __restrict__ Ahi, const ushort* __restrict__ Alo,
    const ushort* __restrict__ Bthi, const ushort* __restrict__ Btlo,
    const float* __restrict__ Bias, float* __restrict__ OUTf,
    ushort* __restrict__ OUThi, ushort* __restrict__ OUTlo, int Nrows)
{
    __shared__ ushort As[2][64][32];    // 8 KB
    __shared__ ushort Ws[2][256][32];   // 32 KB
    const int t    = threadIdx.x;
    const int wv   = t >> 6;
    const int lane = t & 63;
    const int l15  = lane & 15;
    const int l4   = lane >> 4;
    const int row0 = blockIdx.x * 64;
    const int wc0  = wv * 64;

    const int srow   = lane >> 2;                        // staged row within 16-group
    const int schunk = (lane & 3) ^ ((lane >> 3) & 3);   // swizzled source k-chunk
    const int rchunk = (l4 ^ ((l15 >> 1) & 3)) * 8;      // ds_read k-offset (ushorts)

    f32x4 acc[4][4];
#pragma unroll
    for (int m = 0; m < 4; ++m)
#pragma unroll
        for (int n = 0; n < 4; ++n) acc[m][n] = (f32x4){0.f, 0.f, 0.f, 0.f};

    const int agrow = min(row0 + wv * 16 + srow, Nrows - 1);
    const size_t abase = (size_t)agrow * K + schunk * 8;

    for (int k0 = 0; k0 < K; k0 += 32) {
        // W^T staging: 4 row-groups x (hi,lo) per wave, 1KB per instr
#pragma unroll
        for (int j = 0; j < 4; ++j) {
            const int g = wv * 4 + j;
            const size_t wb = (size_t)(g * 16 + srow) * K + k0 + schunk * 8;
            gload16(Bthi + wb, &Ws[0][g * 16][0]);
            gload16(Btlo + wb, &Ws[1][g * 16][0]);
        }
        // A staging: 1 row-group x (hi,lo) per wave
        gload16(Ahi + abase + k0, &As[0][wv * 16][0]);
        gload16(Alo + abase + k0, &As[1][wv * 16][0]);
        __syncthreads();   // drains vmcnt (global_load_lds) + lgkm

        bf16x8 ah[4], al[4], bh[4], bl[4];
#pragma unroll
        for (int m = 0; m < 4; ++m) {
            ah[m] = *(const bf16x8*)&As[0][m * 16 + l15][rchunk];
            al[m] = *(const bf16x8*)&As[1][m * 16 + l15][rchunk];
        }
#pragma unroll
        for (int n = 0; n < 4; ++n) {
            bh[n] = *(const bf16x8*)&Ws[0][wc0 + n * 16 + l15][rchunk];
            bl[n] = *(const bf16x8*)&Ws[1][wc0 + n * 16 + l15][rchunk];
        }
#pragma unroll
        for (int m = 0; m < 4; ++m)
#pragma unroll
            for (int n = 0; n < 4; ++n) {
                acc[m][n] = __builtin_amdgcn_mfma_f32_16x16x32_bf16(ah[m], bh[n], acc[m][n], 0, 0, 0);
                acc[m][n] = __builtin_amdgcn_mfma_f32_16x16x32_bf16(ah[m], bl[n], acc[m][n], 0, 0, 0);
                acc[m][n] = __builtin_amdgcn_mfma_f32_16x16x32_bf16(al[m], bh[n], acc[m][n], 0, 0, 0);
            }
        __syncthreads();
    }

    // epilogue: C/D layout col=lane&15, row=(lane>>4)*4+reg (HW-verified)
#pragma unroll
    for (int n = 0; n < 4; ++n) {
        const int ocol = wc0 + n * 16 + l15;
        const float bs = Bias[ocol];
#pragma unroll
        for (int m = 0; m < 4; ++m) {
#pragma unroll
            for (int r = 0; r < 4; ++r) {
                int orow = row0 + m * 16 + l4 * 4 + r;
                if (orow < Nrows) {
                    float v = fmaxf(acc[m][n][r] + bs, 0.f);
                    size_t o = (size_t)orow * HDIM + ocol;
                    if (SPLIT_OUT) {
                        ushort h = f2bf(v);
                        OUThi[o] = h;
                        OUTlo[o] = f2bf(v - bf2f(h));
                    } else {
                        OUTf[o] = v;
                    }
                }
            }
        }
    }
}

// ---------------------------------------------------------------------------
// pooling phase 1: grid = G * PSPLIT blocks, x4 unrolled row loop
// ---------------------------------------------------------------------------
__global__ __launch_bounds__(256) void pool_partial_kernel(
    const float* __restrict__ h2, const int* __restrict__ batch,
    float* __restrict__ psum, float* __restrict__ pmax, int N)
{
    const int g = blockIdx.x / PSPLIT;
    const int s = blockIdx.x % PSPLIT;
    const int t = threadIdx.x;

    __shared__ int s_bounds[2];
    if (t < 2) {
        int target = g + t;
        int lo = 0, hi = N;
        while (lo < hi) {
            int mid = (lo + hi) >> 1;
            if (batch[mid] < target) lo = mid + 1; else hi = mid;
        }
        s_bounds[t] = lo;
    }
    __syncthreads();
    const int glo = s_bounds[0], ghi = s_bounds[1];
    const int cnt = ghi - glo;
    const int chunk = (cnt + PSPLIT - 1) / PSPLIT;
    const int clo = glo + s * chunk;
    const int chi = min(clo + chunk, ghi);

    float s0 = 0.f, s1 = 0.f, s2 = 0.f, s3 = 0.f;
    float m0 = -INFINITY, m1 = -INFINITY, m2 = -INFINITY, m3 = -INFINITY;
    int n = clo;
    for (; n + 4 <= chi; n += 4) {
        float v0 = h2[(size_t)(n + 0) * HDIM + t];
        float v1 = h2[(size_t)(n + 1) * HDIM + t];
        float v2 = h2[(size_t)(n + 2) * HDIM + t];
        float v3 = h2[(size_t)(n + 3) * HDIM + t];
        s0 += v0; m0 = fmaxf(m0, v0);
        s1 += v1; m1 = fmaxf(m1, v1);
        s2 += v2; m2 = fmaxf(m2, v2);
        s3 += v3; m3 = fmaxf(m3, v3);
    }
    for (; n < chi; ++n) {
        float v = h2[(size_t)n * HDIM + t];
        s0 += v; m0 = fmaxf(m0, v);
    }
    size_t o = (size_t)blockIdx.x * HDIM + t;
    psum[o] = (s0 + s1) + (s2 + s3);
    pmax[o] = fmaxf(fmaxf(m0, m1), fmaxf(m2, m3));
}

// ---------------------------------------------------------------------------
// pooling phase 2 + final MLP: one block per graph
// ---------------------------------------------------------------------------
__global__ __launch_bounds__(256) void pool_final_kernel(
    const float* __restrict__ psum, const float* __restrict__ pmax,
    const int* __restrict__ batch,
    const float* __restrict__ Wf1, const float* __restrict__ bf1,
    const float* __restrict__ Wf2, const float* __restrict__ bf2,
    float* __restrict__ out, int N)
{
    const int g = blockIdx.x;
    const int t = threadIdx.x;

    __shared__ int s_bounds[2];
    if (t < 2) {
        int target = g + t;
        int lo = 0, hi = N;
        while (lo < hi) {
            int mid = (lo + hi) >> 1;
            if (batch[mid] < target) lo = mid + 1; else hi = mid;
        }
        s_bounds[t] = lo;
    }
    __syncthreads();
    const int cnt = s_bounds[1] - s_bounds[0];

    float sum = 0.f, mx = -INFINITY;
    const size_t gbase = (size_t)g * PSPLIT * HDIM + t;
#pragma unroll
    for (int s = 0; s < PSPLIT; ++s) {
        sum += psum[gbase + (size_t)s * HDIM];
        mx = fmaxf(mx, pmax[gbase + (size_t)s * HDIM]);
    }

    __shared__ float p[2 * HDIM];
    p[t]        = sum / (float)(cnt > 1 ? cnt : 1);
    p[HDIM + t] = (cnt > 0) ? mx : 0.f;
    __syncthreads();

    float acc = bf1[t];
#pragma unroll 8
    for (int k = 0; k < 2 * HDIM; ++k)
        acc += p[k] * Wf1[k * HDIM + t];
    float hval = fmaxf(acc, 0.f);

    float partial = hval * Wf2[t];
#pragma unroll
    for (int off = 32; off > 0; off >>= 1)
        partial += __shfl_down(partial, off);
    __shared__ float red[4];
    if ((t & 63) == 0) red[t >> 6] = partial;
    __syncthreads();
    if (t == 0) out[g] = red[0] + red[1] + red[2] + red[3] + bf2[0];
}

// ---------------------------------------------------------------------------
extern "C" void kernel_launch(void* const* d_in, const int* in_sizes, int n_in,
                              void* d_out, int out_size, void* d_ws, size_t ws_size,
                              hipStream_t stream)
{
    const float* x     = (const float*)d_in[0];
    const int*   ei    = (const int*)d_in[1];
    const int*   batch = (const int*)d_in[2];
    const float* W1 = (const float*)d_in[3];
    const float* b1 = (const float*)d_in[4];
    const float* W2 = (const float*)d_in[5];
    const float* b2 = (const float*)d_in[6];
    const float* W3 = (const float*)d_in[7];
    const float* b3 = (const float*)d_in[8];
    const float* W4 = (const float*)d_in[9];
    const float* b4 = (const float*)d_in[10];
    const float* Wf1 = (const float*)d_in[11];
    const float* bf1 = (const float*)d_in[12];
    const float* Wf2 = (const float*)d_in[13];
    const float* bf2 = (const float*)d_in[14];
    float* out = (float*)d_out;

    const int N  = in_sizes[0] / D_IN;   // 50000
    const int E  = in_sizes[1] / 2;      // 600000
    const int Gn = out_size;             // 128

    // ---- workspace layout ----
    const size_t R = (size_t)N * HDIM;   // floats per region
    float* R0f = (float*)d_ws;
    float* R1f = R0f + R;
    ushort* R0u = (ushort*)R0f;
    ushort* R1u = (ushort*)R1f;

    ushort* wbuf = (ushort*)(R1f + R);
    ushort* W1thi = wbuf;
    ushort* W1tlo = W1thi + 128 * 256;
    ushort* W2thi = W1tlo + 128 * 256;
    ushort* W2tlo = W2thi + 256 * 256;
    ushort* W3thi = W2tlo + 256 * 256;
    ushort* W3tlo = W3thi + 256 * 256;
    ushort* W4thi = W3tlo + 256 * 256;
    ushort* W4tlo = W4thi + 256 * 256;

    int* rowptr  = (int*)(W4tlo + 256 * 256);
    int* cursor  = rowptr + (N + 1);
    int* srclist = cursor + N;
    float* psum  = (float*)(srclist + E);
    float* pmax  = psum + (size_t)Gn * PSPLIT * HDIM;
    int* bsum    = (int*)(pmax + (size_t)Gn * PSPLIT * HDIM);

    const int gblocks  = (N + 63) / 64;
    const int eblocks  = (E + 255) / 256;
    const int wblocks2 = (N + 3) / 4;          // gather2: 1 node/wave
    const int wblocks1 = ((N + 1) / 2 + 3) / 4; // gather1: 2 nodes/wave
    const int nb       = (N + 255) / 256;

    // ---- CSR build (multi-block scan) ----
    zero_int_kernel<<<64, 256, 0, stream>>>(cursor, N);
    hist_kernel<<<eblocks, 256, 0, stream>>>(ei, cursor, E);
    scan_local_kernel<<<nb, 256, 0, stream>>>(cursor, rowptr, bsum, N);
    scan_bsum_kernel<<<1, 256, 0, stream>>>(bsum, rowptr, nb, N);
    scan_apply_kernel<<<nb, 256, 0, stream>>>(rowptr, cursor, bsum, N);
    fill_kernel<<<eblocks, 256, 0, stream>>>(ei, cursor, srclist, E);

    // ---- weight split+transpose ----
    wsplit_kernel<128><<<128, 256, 0, stream>>>(W1, W1thi, W1tlo);
    wsplit_kernel<256><<<256, 256, 0, stream>>>(W2, W2thi, W2tlo);
    wsplit_kernel<256><<<256, 256, 0, stream>>>(W3, W3thi, W3tlo);
    wsplit_kernel<256><<<256, 256, 0, stream>>>(W4, W4thi, W4tlo);

    // buffer views
    ushort* Z1hi = R0u;                 ushort* Z1lo = R0u + (size_t)N * D_IN;  // [N][128] split
    ushort* T1hi = R1u;                 ushort* T1lo = R1u + R;                 // [N][256] split
    float*  H1   = R0f;                                                         // [N][256] fp32
    ushort* Z2hi = R1u;                 ushort* Z2lo = R1u + R;                 // [N][256] split
    ushort* T2hi = R0u;                 ushort* T2lo = R0u + R;                 // [N][256] split
    float*  H2   = R1f;                                                         // [N][256] fp32

    // ---- conv1 ----
    gather1_kernel<<<wblocks1, 256, 0, stream>>>(x, rowptr, srclist, Z1hi, Z1lo, N);
    mfma_gemm_kernel<128, true><<<gblocks, 256, 0, stream>>>(
        Z1hi, Z1lo, W1thi, W1tlo, b1, nullptr, T1hi, T1lo, N);
    mfma_gemm_kernel<256, false><<<gblocks, 256, 0, stream>>>(
        T1hi, T1lo, W2thi, W2tlo, b2, H1, nullptr, nullptr, N);

    // ---- conv2 ----
    gather2_kernel<<<wblocks2, 256, 0, stream>>>(H1, rowptr, srclist, Z2hi, Z2lo, N);
    mfma_gemm_kernel<256, true><<<gblocks, 256, 0, stream>>>(
        Z2hi, Z2lo, W3thi, W3tlo, b3, nullptr, T2hi, T2lo, N);
    mfma_gemm_kernel<256, false><<<gblocks, 256, 0, stream>>>(
        T2hi, T2lo, W4thi, W4tlo, b4, H2, nullptr, nullptr, N);

    // ---- pooling (2-phase) + final MLP ----
    pool_partial_kernel<<<Gn * PSPLIT, 256, 0, stream>>>(H2, batch, psum, pmax, N);
    pool_final_kernel<<<Gn, 256, 0, stream>>>(psum, pmax, batch,
                                              Wf1, bf1, Wf2, bf2, out, N);
}